// Round 7
// baseline (454.209 us; speedup 1.0000x reference)
//
#include <hip/hip_runtime.h>
#include <hip/hip_fp16.h>

// LightGCN on MI355X — block-aggregated bucket build + batched-MLP gather,
// deferred-total fp16 pipeline.
//
// Build: LDS bucket histogram -> scan -> block-aggregated pair scatter ->
// per-bucket LDS CSR finalize.
// R9:  bscatter 1024thr/CH=16384 (566->512).
// R10: batched 64-entry adjacency read + dis folded into state (512->481).
// R11: total deferred out of gathers; fp16 state; final pass (481->459).
// R12: bscatter pairs staged in LDS grouped by bucket (459->434).
//      Gather baseline here: 74us, FETCH 217MB (scalar acc, slot0 layout).
// R13: FUSE final into g3 (WIN); float2 acc + BLK128 (gather 74->86us,
//      FETCH 217->261MB).
// R14: BLK revert alone did NOT recover (86us/259MB persists) -> block size
//      exonerated; suspects = float2 codegen (VGPR=28 load-batching
//      schedule) and/or workspace base shift.
// R15: restore R12 gather verbatim (scalar acc2h, slot0 = max(u,p) layout
//      so z0/z1/z2 sit at R12 offsets); keep FUSE + BLK256. Plus
//      non-temporal hints on touch-once streams (csr loads, z/out stores)
//      to stop them evicting the z-gather working set from L2.

#ifndef EMB
#define EMB 64
#endif
#define BSHIFT 7                 // 128 nodes per bucket
#define BNODES (1 << BSHIFT)
#define NBMAX 1280               // LDS histogram capacity
#define CCAP 4800                // LDS pair-staging capacity per bucket
#define CH 16384                 // edges per bscatter block
#define STH 1024                 // bscatter threads per block

typedef unsigned int uint;
typedef unsigned short ushort;
typedef uint  __attribute__((ext_vector_type(4))) uintx4;
typedef float __attribute__((ext_vector_type(4))) floatx4;

static __device__ __forceinline__ ushort f2h(float f) {
    __half h = __float2half(f);
    return *(ushort*)&h;
}

// u = two packed fp16; accumulate {lo,hi} into aL,aH (R12-proven form).
static __device__ __forceinline__ void acc2h(uint u, float& aL, float& aH) {
    __half2 h = *(__half2*)&u;
    float2 f = __half22float2(h);
    aL += f.x;
    aH += f.y;
}

static __device__ __forceinline__ float2 h2f2(uint u) {
    __half2 h = *(__half2*)&u;
    return __half22float2(h);
}

// ---- setup: dtype detect + zero bucket counters + zero dummy rows ----
__global__ void lgcn_setup_kernel(const int* __restrict__ ei,
                                  int* __restrict__ flag,
                                  int* __restrict__ bcount,
                                  int* __restrict__ bcur,
                                  ushort* __restrict__ z0,
                                  ushort* __restrict__ z1,
                                  ushort* __restrict__ z2,
                                  int NB, int n_elems) {
    __shared__ int any_nz;
    int t = threadIdx.x;
    if (t == 0) any_nz = 0;
    __syncthreads();
    if (t < 128 && ei[2 * t + 1] != 0) atomicOr(&any_nz, 1);
    for (int i = t; i < NB; i += 256) { bcount[i] = 0; bcur[i] = 0; }
    if (t < EMB) {
        z0[n_elems + t] = 0;
        z1[n_elems + t] = 0;
        z2[n_elems + t] = 0;
    }
    __syncthreads();
    if (t == 0) *flag = (any_nz == 0) ? 1 : 0;
}

static __device__ __forceinline__ int load_idx(const int* __restrict__ ei,
                                               long long elem, int is64,
                                               int n_nodes) {
    int v = is64 ? ei[elem << 1] : ei[elem];
    return min(max(v, 0), n_nodes - 1);
}

// ---- build step 1: bucket histogram (LDS-staged) ----
__global__ void lgcn_bhist_kernel(const int* __restrict__ ei,
                                  const int* __restrict__ flag,
                                  int* __restrict__ bcount,
                                  int n_edges, int n_nodes, int NB) {
    __shared__ int h[NBMAX];
    int t = threadIdx.x;
    int is64 = *flag;
    for (int i = t; i < NB; i += 256) h[i] = 0;
    __syncthreads();
    long long base = (long long)blockIdx.x * 4096 + t;
    #pragma unroll
    for (int k = 0; k < 16; ++k) {
        long long e = base + (long long)k * 256;
        if (e < n_edges) {
            int c = load_idx(ei, (long long)n_edges + e, is64, n_nodes);
            atomicAdd(&h[c >> BSHIFT], 1);
        }
    }
    __syncthreads();
    for (int i = t; i < NB; i += 256) {
        int v = h[i];
        if (v) atomicAdd(&bcount[i], v);
    }
}

// ---- build step 2: exclusive scan of bucket counts (single block) ----
__global__ void lgcn_bscan_kernel(const int* __restrict__ bcount,
                                  int* __restrict__ bucketBase,
                                  int* __restrict__ offsets,
                                  int NB, int n_nodes) {
    __shared__ int tsum[256];
    int t = threadIdx.x;
    int K = (NB + 255) / 256;
    int base = t * K;
    int s = 0;
    for (int k = 0; k < K; ++k) {
        int i = base + k;
        if (i < NB) s += bcount[i];
    }
    tsum[t] = s;
    __syncthreads();
    for (int off = 1; off < 256; off <<= 1) {
        int x = (t >= off) ? tsum[t - off] : 0;
        __syncthreads();
        tsum[t] += x;
        __syncthreads();
    }
    int run = tsum[t] - s;
    for (int k = 0; k < K; ++k) {
        int i = base + k;
        if (i < NB) { bucketBase[i] = run; run += bcount[i]; }
    }
    if (t == 255) {
        bucketBase[NB] = tsum[255];
        offsets[n_nodes] = tsum[255];
    }
}

// ---- build step 3: block-aggregated pair scatter, LDS-staged (R12) ----
__global__ void __launch_bounds__(STH)
lgcn_bscatter3_kernel(const int* __restrict__ ei,
                      const int* __restrict__ flag,
                      const int* __restrict__ bucketBase,
                      int* __restrict__ bcur,
                      uint* __restrict__ pairs,
                      int n_edges, int n_nodes, int NB) {
    __shared__ int lcount[NBMAX];   // histogram, then staging cursor
    __shared__ int lloc[NBMAX];     // local staging base per bucket
    __shared__ int ldelta[NBMAX];   // global_run_base - local_base
    __shared__ int tsum[STH];
    __shared__ int ltot;
    __shared__ uint stage[CH];      // 64 KB pair staging
    __shared__ ushort stageb[CH];   // 32 KB bucket id per staged pair
    int t = threadIdx.x;
    int is64 = *flag;
    long long base = (long long)blockIdx.x * CH;
    for (int i = t; i < NB; i += STH) lcount[i] = 0;
    __syncthreads();
    // pass 1: local histogram of target buckets
    for (int k = t; k < CH; k += STH) {
        long long e = base + k;
        if (e < n_edges) {
            int c = load_idx(ei, (long long)n_edges + e, is64, n_nodes);
            atomicAdd(&lcount[c >> BSHIFT], 1);
        }
    }
    __syncthreads();
    // local exclusive scan lcount -> lloc (staging layout)
    {
        int K = (NB + STH - 1) / STH;
        int cbase = t * K;
        int s = 0;
        for (int k = 0; k < K; ++k) {
            int i = cbase + k;
            if (i < NB) s += lcount[i];
        }
        tsum[t] = s;
        __syncthreads();
        for (int off = 1; off < STH; off <<= 1) {
            int x = (t >= off) ? tsum[t - off] : 0;
            __syncthreads();
            tsum[t] += x;
            __syncthreads();
        }
        int run = tsum[t] - s;
        for (int k = 0; k < K; ++k) {
            int i = cbase + k;
            if (i < NB) { lloc[i] = run; run += lcount[i]; }
        }
        if (t == STH - 1) ltot = tsum[t];
    }
    __syncthreads();
    // reservation: one global atomic per non-empty bucket
    for (int i = t; i < NB; i += STH) {
        int cnt = lcount[i];
        ldelta[i] = cnt ? (bucketBase[i] + atomicAdd(&bcur[i], cnt) - lloc[i]) : 0;
        lcount[i] = 0;   // reuse as staging cursor
    }
    __syncthreads();
    // pass 2: stage pairs grouped by bucket in LDS
    for (int k = t; k < CH; k += STH) {
        long long e = base + k;
        if (e < n_edges) {
            int r = load_idx(ei, e, is64, n_nodes);
            int c = load_idx(ei, (long long)n_edges + e, is64, n_nodes);
            int b = c >> BSHIFT;
            int pos = lloc[b] + atomicAdd(&lcount[b], 1);
            stage[pos] = ((uint)r << BSHIFT) | (uint)(c & (BNODES - 1));
            stageb[pos] = (ushort)b;
        }
    }
    __syncthreads();
    // pass 3: coalesced run-contiguous global writes
    int tot = ltot;
    for (int k = t; k < tot; k += STH) {
        pairs[ldelta[stageb[k]] + k] = stage[k];
    }
}

// ---- build step 4: per-bucket CSR finalize + fused z0 init ----
__global__ void lgcn_bcsr_kernel(const uint* __restrict__ pairs,
                                 const int* __restrict__ bucketBase,
                                 const float* __restrict__ user_w,
                                 const float* __restrict__ item_w,
                                 int* __restrict__ offsets,
                                 int* __restrict__ csr_rows,
                                 float* __restrict__ dis,
                                 ushort* __restrict__ z0,
                                 int n_user_elems, int n_nodes) {
    __shared__ int deg[BNODES];
    __shared__ int tmp[BNODES];
    __shared__ int loffx[BNODES];
    __shared__ int cur[BNODES];
    __shared__ float disL[BNODES];
    __shared__ uint lp[CCAP];
    int b = blockIdx.x;
    int t = threadIdx.x;            // 256 threads
    int nodeStart = b << BSHIFT;
    int base = bucketBase[b];
    int span = bucketBase[b + 1] - base;
    bool fits = (span <= CCAP);
    if (t < BNODES) deg[t] = 0;
    __syncthreads();
    for (int i = t; i < span; i += 256) {
        uint p = pairs[base + i];
        if (fits) lp[i] = p;
        atomicAdd(&deg[p & (BNODES - 1)], 1);
    }
    __syncthreads();
    if (t < BNODES) tmp[t] = deg[t];
    __syncthreads();
    for (int off = 1; off < BNODES; off <<= 1) {
        int x = (t < BNODES && t >= off) ? tmp[t - off] : 0;
        __syncthreads();
        if (t < BNODES) tmp[t] += x;
        __syncthreads();
    }
    if (t < BNODES) {
        int excl = tmp[t] - deg[t];
        loffx[t] = excl;
        cur[t] = 0;
        float d = (deg[t] > 0) ? rsqrtf((float)deg[t]) : 0.0f;
        disL[t] = d;
        int node = nodeStart + t;
        if (node < n_nodes) {
            offsets[node] = base + excl;
            dis[node] = d;
        }
    }
    __syncthreads();
    for (int i = t; i < span; i += 256) {
        uint p = fits ? lp[i] : pairs[base + i];
        int cl = (int)(p & (BNODES - 1));
        int pos = loffx[cl] + atomicAdd(&cur[cl], 1);
        csr_rows[base + pos] = (int)(p >> BSHIFT);
    }
    // fused init: z0 rows for this bucket's nodes, z0 = fp16(dis * x)
    int eBase = nodeStart << 6;               // first element of this bucket
    for (int e4 = t; e4 < (BNODES << 4); e4 += 256) {   // float4 granules
        int e = e4 << 2;
        int node = nodeStart + (e >> 6);
        if (node < n_nodes) {
            int gi = eBase + e;
            float4 v = (gi < n_user_elems)
                ? *(const float4*)(user_w + gi)
                : *(const float4*)(item_w + (gi - n_user_elems));
            float d = disL[e >> 6];
            ushort4 o;
            o.x = f2h(d * v.x); o.y = f2h(d * v.y);
            o.z = f2h(d * v.z); o.w = f2h(d * v.w);
            *(ushort4*)(z0 + gi) = o;
        }
    }
}

// gather: one wave per node; 8 lanes per edge (uint4 = 16B per lane).
// R12-proven body: scalar acc2h into a[8]; up to 64 adjacency entries in
// one coalesced (non-temporal) csr read; all row gathers back-to-back.
// FUSE (layer 3): epilogue computes out = 0.25*(x + inv*(z1+z2) + dc*sum).
// z/out stores are non-temporal (touch-once) to preserve L2 for z-gathers.
template <bool FUSE>
__global__ void lgcn_gather_kernel(const int* __restrict__ csr_rows,
                                   const int* __restrict__ offsets,
                                   const float* __restrict__ dis,
                                   const ushort* __restrict__ zin,
                                   ushort* __restrict__ zout,
                                   const ushort* __restrict__ zprev,
                                   const float* __restrict__ user_w,
                                   const float* __restrict__ item_w,
                                   float* __restrict__ out,
                                   int n_user_elems, int n_nodes) {
    long long tid = (long long)blockIdx.x * blockDim.x + threadIdx.x;
    int c    = (int)(tid >> 6);
    int lane = threadIdx.x & 63;
    int oct  = lane >> 3;   // edge slot 0..7 within a group
    int o8   = lane & 7;    // which 16B chunk of the 128B row
    if (c >= n_nodes) return;
    int beg = offsets[c];
    int end = offsets[c + 1];
    int deg = end - beg;
    float a[8];
    #pragma unroll
    for (int k = 0; k < 8; ++k) a[k] = 0.0f;

    if (deg > 0) {
        int n1 = deg < 64 ? deg : 64;
        int ng = (n1 + 7) >> 3;        // active groups (wave-uniform)
        int rr[8];
        #pragma unroll
        for (int g = 0; g < 8; ++g) {
            int s = g * 8 + oct;
            if (g < ng) {
                int r = __builtin_nontemporal_load(csr_rows + beg + (s < n1 ? s : 0));
                rr[g] = (s < n1) ? r : n_nodes;      // zero row for tail
            } else {
                rr[g] = n_nodes;
            }
        }
        uint4 q[8];
        #pragma unroll
        for (int g = 0; g < 8; ++g)
            if (g < ng)
                q[g] = *(const uint4*)(zin + (size_t)rr[g] * EMB + o8 * 8);
        #pragma unroll
        for (int g = 0; g < 8; ++g) {
            if (g < ng) {
                acc2h(q[g].x, a[0], a[1]);
                acc2h(q[g].y, a[2], a[3]);
                acc2h(q[g].z, a[4], a[5]);
                acc2h(q[g].w, a[6], a[7]);
            }
        }
        // rare tail: deg > 64
        for (int j = beg + 64; j < end; j += 16) {
            int j0 = j + oct;
            int j1 = j + 8 + oct;
            bool v0 = j0 < end;
            bool v1 = j1 < end;
            int r0 = __builtin_nontemporal_load(csr_rows + (v0 ? j0 : beg));
            r0 = v0 ? r0 : n_nodes;
            int r1 = __builtin_nontemporal_load(csr_rows + (v1 ? j1 : beg));
            r1 = v1 ? r1 : n_nodes;
            uint4 q0 = *(const uint4*)(zin + (size_t)r0 * EMB + o8 * 8);
            uint4 q1 = *(const uint4*)(zin + (size_t)r1 * EMB + o8 * 8);
            acc2h(q0.x, a[0], a[1]);
            acc2h(q0.y, a[2], a[3]);
            acc2h(q0.z, a[4], a[5]);
            acc2h(q0.w, a[6], a[7]);
            acc2h(q1.x, a[0], a[1]);
            acc2h(q1.y, a[2], a[3]);
            acc2h(q1.z, a[4], a[5]);
            acc2h(q1.w, a[6], a[7]);
        }
    }

    #pragma unroll
    for (int k = 0; k < 8; ++k) {
        a[k] += __shfl_xor(a[k], 8, 64);
        a[k] += __shfl_xor(a[k], 16, 64);
        a[k] += __shfl_xor(a[k], 32, 64);
    }

    if (oct == 0) {   // lanes 0..7; lane l holds dims [8*l, 8*l+8)
        float dc = dis[c];
        size_t fo = (size_t)c * EMB + o8 * 8;
        if (!FUSE) {
            float s2 = dc * dc;               // z_new = dis^2 * sum
            uintx4 v;
            v.x = ((uint)f2h(s2 * a[1]) << 16) | f2h(s2 * a[0]);
            v.y = ((uint)f2h(s2 * a[3]) << 16) | f2h(s2 * a[2]);
            v.z = ((uint)f2h(s2 * a[5]) << 16) | f2h(s2 * a[4]);
            v.w = ((uint)f2h(s2 * a[7]) << 16) | f2h(s2 * a[6]);
            __builtin_nontemporal_store(v, (uintx4*)(zout + fo));
        } else {
            // out = 0.25*(x + inv*(z1+z2) + dc*sum); inv = 1/dc (0 if deg=0)
            float inv = (dc > 0.0f) ? 1.0f / dc : 0.0f;
            uint4 v1 = *(const uint4*)(zprev + fo);
            uint4 v2 = *(const uint4*)(zin + fo);
            float4 x0, x1;
            if ((int)fo < n_user_elems) {
                x0 = *(const float4*)(user_w + fo);
                x1 = *(const float4*)(user_w + fo + 4);
            } else {
                size_t j = fo - n_user_elems;
                x0 = *(const float4*)(item_w + j);
                x1 = *(const float4*)(item_w + j + 4);
            }
            float2 p, q;
            floatx4 o0, o1;
            p = h2f2(v1.x); q = h2f2(v2.x);
            o0.x = 0.25f * (x0.x + inv * (p.x + q.x) + dc * a[0]);
            o0.y = 0.25f * (x0.y + inv * (p.y + q.y) + dc * a[1]);
            p = h2f2(v1.y); q = h2f2(v2.y);
            o0.z = 0.25f * (x0.z + inv * (p.x + q.x) + dc * a[2]);
            o0.w = 0.25f * (x0.w + inv * (p.y + q.y) + dc * a[3]);
            p = h2f2(v1.z); q = h2f2(v2.z);
            o1.x = 0.25f * (x1.x + inv * (p.x + q.x) + dc * a[4]);
            o1.y = 0.25f * (x1.y + inv * (p.y + q.y) + dc * a[5]);
            p = h2f2(v1.w); q = h2f2(v2.w);
            o1.z = 0.25f * (x1.z + inv * (p.x + q.x) + dc * a[6]);
            o1.w = 0.25f * (x1.w + inv * (p.y + q.y) + dc * a[7]);
            __builtin_nontemporal_store(o0, (floatx4*)(out + fo));
            __builtin_nontemporal_store(o1, (floatx4*)(out + fo + 4));
        }
    }
}

extern "C" void kernel_launch(void* const* d_in, const int* in_sizes, int n_in,
                              void* d_out, int out_size, void* d_ws, size_t ws_size,
                              hipStream_t stream) {
    // ---- role assignment by element count ----
    int ie = 0, iu = 1, ii = 2;
    {
        long long s[3] = { in_sizes[0], in_sizes[1], in_sizes[2] };
        ie = 0;
        if (s[1] > s[ie]) ie = 1;
        if (s[2] > s[ie]) ie = 2;
        int rest[2], k = 0;
        for (int j = 0; j < 3; ++j) if (j != ie) rest[k++] = j;
        if (s[rest[0]] >= s[rest[1]]) { iu = rest[0]; ii = rest[1]; }
        else                          { iu = rest[1]; ii = rest[0]; }
    }
    const int*   edge_index = (const int*)d_in[ie];
    const float* user_w     = (const float*)d_in[iu];
    const float* item_w     = (const float*)d_in[ii];
    float* out = (float*)d_out;

    const int n_edges = in_sizes[ie] / 2;
    const int n_users = in_sizes[iu] / EMB;
    const int n_items = in_sizes[ii] / EMB;
    const int n_nodes = n_users + n_items;
    const int n_elems = n_nodes * EMB;
    const int NB = (n_nodes + BNODES - 1) / BNODES;   // 1172

    // ---- workspace carve (~93 MB; R12 layout restored: pairs in slot0) ----
    // fp16 state buffers each have one extra zero row at node index n_nodes.
    auto align_up = [](size_t x) { return (x + 1023) & ~(size_t)1023; };
    char* w = (char*)d_ws;
    int*   flag       = (int*)w; w += 1024;
    int*   bcount     = (int*)w; w += align_up((size_t)NB * sizeof(int));
    int*   bucketBase = (int*)w; w += align_up(((size_t)NB + 1) * sizeof(int));
    int*   bcur       = (int*)w; w += align_up((size_t)NB * sizeof(int));
    int*   offsets    = (int*)w; w += align_up(((size_t)n_nodes + 1) * sizeof(int));
    float* dis        = (float*)w; w += align_up((size_t)n_nodes * sizeof(float));
    int*   csr_rows   = (int*)w; w += align_up((size_t)n_edges * sizeof(int));
    size_t u_bytes = align_up(((size_t)n_elems + EMB) * sizeof(ushort));
    size_t p_bytes = align_up((size_t)n_edges * sizeof(uint));
    size_t slot0   = (u_bytes > p_bytes ? u_bytes : p_bytes);
    uint*   pairs = (uint*)w; w += slot0;        // R12 slot sizing
    ushort* z0    = (ushort*)w; w += u_bytes;
    ushort* z1    = (ushort*)w; w += u_bytes;
    ushort* z2    = (ushort*)w; w += u_bytes;

    // 0) setup: dtype detect + zero counters + zero dummy rows
    lgcn_setup_kernel<<<1, 256, 0, stream>>>(edge_index, flag, bcount, bcur,
                                             z0, z1, z2, NB, n_elems);

    // 1) bucket histogram -> scan -> staged scatter -> bucket CSR(+init)
    lgcn_bhist_kernel<<<(n_edges + 4095) / 4096, 256, 0, stream>>>(
        edge_index, flag, bcount, n_edges, n_nodes, NB);
    lgcn_bscan_kernel<<<1, 256, 0, stream>>>(bcount, bucketBase, offsets, NB, n_nodes);
    lgcn_bscatter3_kernel<<<(n_edges + CH - 1) / CH, STH, 0, stream>>>(
        edge_index, flag, bucketBase, bcur, pairs, n_edges, n_nodes, NB);
    lgcn_bcsr_kernel<<<NB, 256, 0, stream>>>(
        pairs, bucketBase, user_w, item_w, offsets, csr_rows, dis, z0,
        n_users * EMB, n_nodes);

    // 2) 3 pull layers: z0 -> z1 -> z2 -> (fused) out
    {
        const int BLK = 256;   // 4 nodes/block
        long long n_thr = (long long)n_nodes * 64;
        int gW = (int)((n_thr + BLK - 1) / BLK);
        lgcn_gather_kernel<false><<<gW, BLK, 0, stream>>>(
            csr_rows, offsets, dis, z0, z1,
            nullptr, nullptr, nullptr, nullptr, 0, n_nodes);
        lgcn_gather_kernel<false><<<gW, BLK, 0, stream>>>(
            csr_rows, offsets, dis, z1, z2,
            nullptr, nullptr, nullptr, nullptr, 0, n_nodes);
        lgcn_gather_kernel<true><<<gW, BLK, 0, stream>>>(
            csr_rows, offsets, dis, z2, nullptr,
            z1, user_w, item_w, out, n_users * EMB, n_nodes);
    }
}

// Round 8
// 421.931 us; speedup vs baseline: 1.0765x; 1.0765x over previous
//
#include <hip/hip_runtime.h>
#include <hip/hip_fp16.h>

// LightGCN on MI355X — block-aggregated bucket build + batched-MLP gather,
// deferred-total fp16 pipeline.
//
// Build: LDS bucket histogram -> scan -> block-aggregated pair scatter ->
// per-bucket LDS CSR finalize.
// R9:  bscatter 1024thr/CH=16384 (566->512).
// R10: batched 64-entry adjacency read + dis folded into state (512->481).
// R11: total deferred out of gathers; fp16 state; final pass (481->459).
// R12: bscatter pairs staged in LDS grouped by bucket (459->434).
// R13: FUSE final into g3 (WIN, kept). float2 acc + BLK128 regressed gather
//      74->86us / FETCH 217->259MB.
// R14: BLK revert -> no recovery. R15: scalar-acc + layout revert -> no
//      recovery either. 86us/259MB is the real steady state for this
//      structure (random-128B fabric regime; ~1.5x per-XCD L2-miss floor;
//      MLP ample by Little's law). R12's 74us = favorable cache-state noise.
// R15 also added non-temporal hints: REGRESSION (424->454). NT stores on
//      z_out evict the very lines the NEXT layer re-reads; NT loads on csr
//      defeat cross-layer L3 reuse. All NT hints removed.
// R16: pure NT revert — back to R14 config (scalar acc2h, BLK256, FUSE,
//      R12 slot0 layout). Next target: the ~167us build phase.

#ifndef EMB
#define EMB 64
#endif
#define BSHIFT 7                 // 128 nodes per bucket
#define BNODES (1 << BSHIFT)
#define NBMAX 1280               // LDS histogram capacity
#define CCAP 4800                // LDS pair-staging capacity per bucket
#define CH 16384                 // edges per bscatter block
#define STH 1024                 // bscatter threads per block

typedef unsigned int uint;
typedef unsigned short ushort;

static __device__ __forceinline__ ushort f2h(float f) {
    __half h = __float2half(f);
    return *(ushort*)&h;
}

// u = two packed fp16; accumulate {lo,hi} into aL,aH (R12-proven form).
static __device__ __forceinline__ void acc2h(uint u, float& aL, float& aH) {
    __half2 h = *(__half2*)&u;
    float2 f = __half22float2(h);
    aL += f.x;
    aH += f.y;
}

static __device__ __forceinline__ float2 h2f2(uint u) {
    __half2 h = *(__half2*)&u;
    return __half22float2(h);
}

// ---- setup: dtype detect + zero bucket counters + zero dummy rows ----
__global__ void lgcn_setup_kernel(const int* __restrict__ ei,
                                  int* __restrict__ flag,
                                  int* __restrict__ bcount,
                                  int* __restrict__ bcur,
                                  ushort* __restrict__ z0,
                                  ushort* __restrict__ z1,
                                  ushort* __restrict__ z2,
                                  int NB, int n_elems) {
    __shared__ int any_nz;
    int t = threadIdx.x;
    if (t == 0) any_nz = 0;
    __syncthreads();
    if (t < 128 && ei[2 * t + 1] != 0) atomicOr(&any_nz, 1);
    for (int i = t; i < NB; i += 256) { bcount[i] = 0; bcur[i] = 0; }
    if (t < EMB) {
        z0[n_elems + t] = 0;
        z1[n_elems + t] = 0;
        z2[n_elems + t] = 0;
    }
    __syncthreads();
    if (t == 0) *flag = (any_nz == 0) ? 1 : 0;
}

static __device__ __forceinline__ int load_idx(const int* __restrict__ ei,
                                               long long elem, int is64,
                                               int n_nodes) {
    int v = is64 ? ei[elem << 1] : ei[elem];
    return min(max(v, 0), n_nodes - 1);
}

// ---- build step 1: bucket histogram (LDS-staged) ----
__global__ void lgcn_bhist_kernel(const int* __restrict__ ei,
                                  const int* __restrict__ flag,
                                  int* __restrict__ bcount,
                                  int n_edges, int n_nodes, int NB) {
    __shared__ int h[NBMAX];
    int t = threadIdx.x;
    int is64 = *flag;
    for (int i = t; i < NB; i += 256) h[i] = 0;
    __syncthreads();
    long long base = (long long)blockIdx.x * 4096 + t;
    #pragma unroll
    for (int k = 0; k < 16; ++k) {
        long long e = base + (long long)k * 256;
        if (e < n_edges) {
            int c = load_idx(ei, (long long)n_edges + e, is64, n_nodes);
            atomicAdd(&h[c >> BSHIFT], 1);
        }
    }
    __syncthreads();
    for (int i = t; i < NB; i += 256) {
        int v = h[i];
        if (v) atomicAdd(&bcount[i], v);
    }
}

// ---- build step 2: exclusive scan of bucket counts (single block) ----
__global__ void lgcn_bscan_kernel(const int* __restrict__ bcount,
                                  int* __restrict__ bucketBase,
                                  int* __restrict__ offsets,
                                  int NB, int n_nodes) {
    __shared__ int tsum[256];
    int t = threadIdx.x;
    int K = (NB + 255) / 256;
    int base = t * K;
    int s = 0;
    for (int k = 0; k < K; ++k) {
        int i = base + k;
        if (i < NB) s += bcount[i];
    }
    tsum[t] = s;
    __syncthreads();
    for (int off = 1; off < 256; off <<= 1) {
        int x = (t >= off) ? tsum[t - off] : 0;
        __syncthreads();
        tsum[t] += x;
        __syncthreads();
    }
    int run = tsum[t] - s;
    for (int k = 0; k < K; ++k) {
        int i = base + k;
        if (i < NB) { bucketBase[i] = run; run += bcount[i]; }
    }
    if (t == 255) {
        bucketBase[NB] = tsum[255];
        offsets[n_nodes] = tsum[255];
    }
}

// ---- build step 3: block-aggregated pair scatter, LDS-staged (R12) ----
__global__ void __launch_bounds__(STH)
lgcn_bscatter3_kernel(const int* __restrict__ ei,
                      const int* __restrict__ flag,
                      const int* __restrict__ bucketBase,
                      int* __restrict__ bcur,
                      uint* __restrict__ pairs,
                      int n_edges, int n_nodes, int NB) {
    __shared__ int lcount[NBMAX];   // histogram, then staging cursor
    __shared__ int lloc[NBMAX];     // local staging base per bucket
    __shared__ int ldelta[NBMAX];   // global_run_base - local_base
    __shared__ int tsum[STH];
    __shared__ int ltot;
    __shared__ uint stage[CH];      // 64 KB pair staging
    __shared__ ushort stageb[CH];   // 32 KB bucket id per staged pair
    int t = threadIdx.x;
    int is64 = *flag;
    long long base = (long long)blockIdx.x * CH;
    for (int i = t; i < NB; i += STH) lcount[i] = 0;
    __syncthreads();
    // pass 1: local histogram of target buckets
    for (int k = t; k < CH; k += STH) {
        long long e = base + k;
        if (e < n_edges) {
            int c = load_idx(ei, (long long)n_edges + e, is64, n_nodes);
            atomicAdd(&lcount[c >> BSHIFT], 1);
        }
    }
    __syncthreads();
    // local exclusive scan lcount -> lloc (staging layout)
    {
        int K = (NB + STH - 1) / STH;
        int cbase = t * K;
        int s = 0;
        for (int k = 0; k < K; ++k) {
            int i = cbase + k;
            if (i < NB) s += lcount[i];
        }
        tsum[t] = s;
        __syncthreads();
        for (int off = 1; off < STH; off <<= 1) {
            int x = (t >= off) ? tsum[t - off] : 0;
            __syncthreads();
            tsum[t] += x;
            __syncthreads();
        }
        int run = tsum[t] - s;
        for (int k = 0; k < K; ++k) {
            int i = cbase + k;
            if (i < NB) { lloc[i] = run; run += lcount[i]; }
        }
        if (t == STH - 1) ltot = tsum[t];
    }
    __syncthreads();
    // reservation: one global atomic per non-empty bucket
    for (int i = t; i < NB; i += STH) {
        int cnt = lcount[i];
        ldelta[i] = cnt ? (bucketBase[i] + atomicAdd(&bcur[i], cnt) - lloc[i]) : 0;
        lcount[i] = 0;   // reuse as staging cursor
    }
    __syncthreads();
    // pass 2: stage pairs grouped by bucket in LDS
    for (int k = t; k < CH; k += STH) {
        long long e = base + k;
        if (e < n_edges) {
            int r = load_idx(ei, e, is64, n_nodes);
            int c = load_idx(ei, (long long)n_edges + e, is64, n_nodes);
            int b = c >> BSHIFT;
            int pos = lloc[b] + atomicAdd(&lcount[b], 1);
            stage[pos] = ((uint)r << BSHIFT) | (uint)(c & (BNODES - 1));
            stageb[pos] = (ushort)b;
        }
    }
    __syncthreads();
    // pass 3: coalesced run-contiguous global writes
    int tot = ltot;
    for (int k = t; k < tot; k += STH) {
        pairs[ldelta[stageb[k]] + k] = stage[k];
    }
}

// ---- build step 4: per-bucket CSR finalize + fused z0 init ----
__global__ void lgcn_bcsr_kernel(const uint* __restrict__ pairs,
                                 const int* __restrict__ bucketBase,
                                 const float* __restrict__ user_w,
                                 const float* __restrict__ item_w,
                                 int* __restrict__ offsets,
                                 int* __restrict__ csr_rows,
                                 float* __restrict__ dis,
                                 ushort* __restrict__ z0,
                                 int n_user_elems, int n_nodes) {
    __shared__ int deg[BNODES];
    __shared__ int tmp[BNODES];
    __shared__ int loffx[BNODES];
    __shared__ int cur[BNODES];
    __shared__ float disL[BNODES];
    __shared__ uint lp[CCAP];
    int b = blockIdx.x;
    int t = threadIdx.x;            // 256 threads
    int nodeStart = b << BSHIFT;
    int base = bucketBase[b];
    int span = bucketBase[b + 1] - base;
    bool fits = (span <= CCAP);
    if (t < BNODES) deg[t] = 0;
    __syncthreads();
    for (int i = t; i < span; i += 256) {
        uint p = pairs[base + i];
        if (fits) lp[i] = p;
        atomicAdd(&deg[p & (BNODES - 1)], 1);
    }
    __syncthreads();
    if (t < BNODES) tmp[t] = deg[t];
    __syncthreads();
    for (int off = 1; off < BNODES; off <<= 1) {
        int x = (t < BNODES && t >= off) ? tmp[t - off] : 0;
        __syncthreads();
        if (t < BNODES) tmp[t] += x;
        __syncthreads();
    }
    if (t < BNODES) {
        int excl = tmp[t] - deg[t];
        loffx[t] = excl;
        cur[t] = 0;
        float d = (deg[t] > 0) ? rsqrtf((float)deg[t]) : 0.0f;
        disL[t] = d;
        int node = nodeStart + t;
        if (node < n_nodes) {
            offsets[node] = base + excl;
            dis[node] = d;
        }
    }
    __syncthreads();
    for (int i = t; i < span; i += 256) {
        uint p = fits ? lp[i] : pairs[base + i];
        int cl = (int)(p & (BNODES - 1));
        int pos = loffx[cl] + atomicAdd(&cur[cl], 1);
        csr_rows[base + pos] = (int)(p >> BSHIFT);
    }
    // fused init: z0 rows for this bucket's nodes, z0 = fp16(dis * x)
    int eBase = nodeStart << 6;               // first element of this bucket
    for (int e4 = t; e4 < (BNODES << 4); e4 += 256) {   // float4 granules
        int e = e4 << 2;
        int node = nodeStart + (e >> 6);
        if (node < n_nodes) {
            int gi = eBase + e;
            float4 v = (gi < n_user_elems)
                ? *(const float4*)(user_w + gi)
                : *(const float4*)(item_w + (gi - n_user_elems));
            float d = disL[e >> 6];
            ushort4 o;
            o.x = f2h(d * v.x); o.y = f2h(d * v.y);
            o.z = f2h(d * v.z); o.w = f2h(d * v.w);
            *(ushort4*)(z0 + gi) = o;
        }
    }
}

// gather: one wave per node; 8 lanes per edge (uint4 = 16B per lane).
// R12-proven body: scalar acc2h into a[8]; up to 64 adjacency entries in
// one coalesced csr read; all row gathers back-to-back.
// FUSE (layer 3): epilogue computes out = 0.25*(x + inv*(z1+z2) + dc*sum).
template <bool FUSE>
__global__ void lgcn_gather_kernel(const int* __restrict__ csr_rows,
                                   const int* __restrict__ offsets,
                                   const float* __restrict__ dis,
                                   const ushort* __restrict__ zin,
                                   ushort* __restrict__ zout,
                                   const ushort* __restrict__ zprev,
                                   const float* __restrict__ user_w,
                                   const float* __restrict__ item_w,
                                   float* __restrict__ out,
                                   int n_user_elems, int n_nodes) {
    long long tid = (long long)blockIdx.x * blockDim.x + threadIdx.x;
    int c    = (int)(tid >> 6);
    int lane = threadIdx.x & 63;
    int oct  = lane >> 3;   // edge slot 0..7 within a group
    int o8   = lane & 7;    // which 16B chunk of the 128B row
    if (c >= n_nodes) return;
    int beg = offsets[c];
    int end = offsets[c + 1];
    int deg = end - beg;
    float a[8];
    #pragma unroll
    for (int k = 0; k < 8; ++k) a[k] = 0.0f;

    if (deg > 0) {
        int n1 = deg < 64 ? deg : 64;
        int ng = (n1 + 7) >> 3;        // active groups (wave-uniform)
        int rr[8];
        #pragma unroll
        for (int g = 0; g < 8; ++g) {
            int s = g * 8 + oct;
            if (g < ng) {
                int r = csr_rows[beg + (s < n1 ? s : 0)];
                rr[g] = (s < n1) ? r : n_nodes;      // zero row for tail
            } else {
                rr[g] = n_nodes;
            }
        }
        uint4 q[8];
        #pragma unroll
        for (int g = 0; g < 8; ++g)
            if (g < ng)
                q[g] = *(const uint4*)(zin + (size_t)rr[g] * EMB + o8 * 8);
        #pragma unroll
        for (int g = 0; g < 8; ++g) {
            if (g < ng) {
                acc2h(q[g].x, a[0], a[1]);
                acc2h(q[g].y, a[2], a[3]);
                acc2h(q[g].z, a[4], a[5]);
                acc2h(q[g].w, a[6], a[7]);
            }
        }
        // rare tail: deg > 64
        for (int j = beg + 64; j < end; j += 16) {
            int j0 = j + oct;
            int j1 = j + 8 + oct;
            bool v0 = j0 < end;
            bool v1 = j1 < end;
            int r0 = csr_rows[v0 ? j0 : beg]; r0 = v0 ? r0 : n_nodes;
            int r1 = csr_rows[v1 ? j1 : beg]; r1 = v1 ? r1 : n_nodes;
            uint4 q0 = *(const uint4*)(zin + (size_t)r0 * EMB + o8 * 8);
            uint4 q1 = *(const uint4*)(zin + (size_t)r1 * EMB + o8 * 8);
            acc2h(q0.x, a[0], a[1]);
            acc2h(q0.y, a[2], a[3]);
            acc2h(q0.z, a[4], a[5]);
            acc2h(q0.w, a[6], a[7]);
            acc2h(q1.x, a[0], a[1]);
            acc2h(q1.y, a[2], a[3]);
            acc2h(q1.z, a[4], a[5]);
            acc2h(q1.w, a[6], a[7]);
        }
    }

    #pragma unroll
    for (int k = 0; k < 8; ++k) {
        a[k] += __shfl_xor(a[k], 8, 64);
        a[k] += __shfl_xor(a[k], 16, 64);
        a[k] += __shfl_xor(a[k], 32, 64);
    }

    if (oct == 0) {   // lanes 0..7; lane l holds dims [8*l, 8*l+8)
        float dc = dis[c];
        size_t fo = (size_t)c * EMB + o8 * 8;
        if (!FUSE) {
            float s2 = dc * dc;               // z_new = dis^2 * sum
            uint4 v;
            v.x = ((uint)f2h(s2 * a[1]) << 16) | f2h(s2 * a[0]);
            v.y = ((uint)f2h(s2 * a[3]) << 16) | f2h(s2 * a[2]);
            v.z = ((uint)f2h(s2 * a[5]) << 16) | f2h(s2 * a[4]);
            v.w = ((uint)f2h(s2 * a[7]) << 16) | f2h(s2 * a[6]);
            *(uint4*)(zout + fo) = v;
        } else {
            // out = 0.25*(x + inv*(z1+z2) + dc*sum); inv = 1/dc (0 if deg=0)
            float inv = (dc > 0.0f) ? 1.0f / dc : 0.0f;
            uint4 v1 = *(const uint4*)(zprev + fo);
            uint4 v2 = *(const uint4*)(zin + fo);
            float4 x0, x1;
            if ((int)fo < n_user_elems) {
                x0 = *(const float4*)(user_w + fo);
                x1 = *(const float4*)(user_w + fo + 4);
            } else {
                size_t j = fo - n_user_elems;
                x0 = *(const float4*)(item_w + j);
                x1 = *(const float4*)(item_w + j + 4);
            }
            float2 p, q;
            float4 o0, o1;
            p = h2f2(v1.x); q = h2f2(v2.x);
            o0.x = 0.25f * (x0.x + inv * (p.x + q.x) + dc * a[0]);
            o0.y = 0.25f * (x0.y + inv * (p.y + q.y) + dc * a[1]);
            p = h2f2(v1.y); q = h2f2(v2.y);
            o0.z = 0.25f * (x0.z + inv * (p.x + q.x) + dc * a[2]);
            o0.w = 0.25f * (x0.w + inv * (p.y + q.y) + dc * a[3]);
            p = h2f2(v1.z); q = h2f2(v2.z);
            o1.x = 0.25f * (x1.x + inv * (p.x + q.x) + dc * a[4]);
            o1.y = 0.25f * (x1.y + inv * (p.y + q.y) + dc * a[5]);
            p = h2f2(v1.w); q = h2f2(v2.w);
            o1.z = 0.25f * (x1.z + inv * (p.x + q.x) + dc * a[6]);
            o1.w = 0.25f * (x1.w + inv * (p.y + q.y) + dc * a[7]);
            *(float4*)(out + fo) = o0;
            *(float4*)(out + fo + 4) = o1;
        }
    }
}

extern "C" void kernel_launch(void* const* d_in, const int* in_sizes, int n_in,
                              void* d_out, int out_size, void* d_ws, size_t ws_size,
                              hipStream_t stream) {
    // ---- role assignment by element count ----
    int ie = 0, iu = 1, ii = 2;
    {
        long long s[3] = { in_sizes[0], in_sizes[1], in_sizes[2] };
        ie = 0;
        if (s[1] > s[ie]) ie = 1;
        if (s[2] > s[ie]) ie = 2;
        int rest[2], k = 0;
        for (int j = 0; j < 3; ++j) if (j != ie) rest[k++] = j;
        if (s[rest[0]] >= s[rest[1]]) { iu = rest[0]; ii = rest[1]; }
        else                          { iu = rest[1]; ii = rest[0]; }
    }
    const int*   edge_index = (const int*)d_in[ie];
    const float* user_w     = (const float*)d_in[iu];
    const float* item_w     = (const float*)d_in[ii];
    float* out = (float*)d_out;

    const int n_edges = in_sizes[ie] / 2;
    const int n_users = in_sizes[iu] / EMB;
    const int n_items = in_sizes[ii] / EMB;
    const int n_nodes = n_users + n_items;
    const int n_elems = n_nodes * EMB;
    const int NB = (n_nodes + BNODES - 1) / BNODES;   // 1172

    // ---- workspace carve (~93 MB; R12 layout: pairs in slot0) ----
    // fp16 state buffers each have one extra zero row at node index n_nodes.
    auto align_up = [](size_t x) { return (x + 1023) & ~(size_t)1023; };
    char* w = (char*)d_ws;
    int*   flag       = (int*)w; w += 1024;
    int*   bcount     = (int*)w; w += align_up((size_t)NB * sizeof(int));
    int*   bucketBase = (int*)w; w += align_up(((size_t)NB + 1) * sizeof(int));
    int*   bcur       = (int*)w; w += align_up((size_t)NB * sizeof(int));
    int*   offsets    = (int*)w; w += align_up(((size_t)n_nodes + 1) * sizeof(int));
    float* dis        = (float*)w; w += align_up((size_t)n_nodes * sizeof(float));
    int*   csr_rows   = (int*)w; w += align_up((size_t)n_edges * sizeof(int));
    size_t u_bytes = align_up(((size_t)n_elems + EMB) * sizeof(ushort));
    size_t p_bytes = align_up((size_t)n_edges * sizeof(uint));
    size_t slot0   = (u_bytes > p_bytes ? u_bytes : p_bytes);
    uint*   pairs = (uint*)w; w += slot0;        // R12 slot sizing
    ushort* z0    = (ushort*)w; w += u_bytes;
    ushort* z1    = (ushort*)w; w += u_bytes;
    ushort* z2    = (ushort*)w; w += u_bytes;

    // 0) setup: dtype detect + zero counters + zero dummy rows
    lgcn_setup_kernel<<<1, 256, 0, stream>>>(edge_index, flag, bcount, bcur,
                                             z0, z1, z2, NB, n_elems);

    // 1) bucket histogram -> scan -> staged scatter -> bucket CSR(+init)
    lgcn_bhist_kernel<<<(n_edges + 4095) / 4096, 256, 0, stream>>>(
        edge_index, flag, bcount, n_edges, n_nodes, NB);
    lgcn_bscan_kernel<<<1, 256, 0, stream>>>(bcount, bucketBase, offsets, NB, n_nodes);
    lgcn_bscatter3_kernel<<<(n_edges + CH - 1) / CH, STH, 0, stream>>>(
        edge_index, flag, bucketBase, bcur, pairs, n_edges, n_nodes, NB);
    lgcn_bcsr_kernel<<<NB, 256, 0, stream>>>(
        pairs, bucketBase, user_w, item_w, offsets, csr_rows, dis, z0,
        n_users * EMB, n_nodes);

    // 2) 3 pull layers: z0 -> z1 -> z2 -> (fused) out
    {
        const int BLK = 256;   // 4 nodes/block
        long long n_thr = (long long)n_nodes * 64;
        int gW = (int)((n_thr + BLK - 1) / BLK);
        lgcn_gather_kernel<false><<<gW, BLK, 0, stream>>>(
            csr_rows, offsets, dis, z0, z1,
            nullptr, nullptr, nullptr, nullptr, 0, n_nodes);
        lgcn_gather_kernel<false><<<gW, BLK, 0, stream>>>(
            csr_rows, offsets, dis, z1, z2,
            nullptr, nullptr, nullptr, nullptr, 0, n_nodes);
        lgcn_gather_kernel<true><<<gW, BLK, 0, stream>>>(
            csr_rows, offsets, dis, z2, nullptr,
            z1, user_w, item_w, out, n_users * EMB, n_nodes);
    }
}

// Round 11
// 417.287 us; speedup vs baseline: 1.0885x; 1.0111x over previous
//
#include <hip/hip_runtime.h>
#include <hip/hip_fp16.h>

// LightGCN on MI355X — bucket build + batched-MLP gather, deferred-total
// fp16 pipeline.
//
// R9:  bscatter 1024thr/CH=16384 (566->512).
// R10: batched 64-entry adjacency read + dis folded into state (512->481).
// R11: total deferred out of gathers; fp16 state; final pass (481->459).
// R12: bscatter pairs staged in LDS grouped by bucket (459->434).
// R13: FUSE final into g3 (WIN). R14/R15: gather 86us/259MB = steady state.
//      R15 NT hints REGRESSED; R16 reverted (454->422). Gather plateau.
// R17/R18: full atomic-free build (bhist2+rowscan+bscatter4) died at
//      container level twice (4 attempts). No fault found in audit, but
//      de-risking: R19 keeps ONLY the highest-value, lowest-risk piece.
// R19: bhist's 1.1M device atomics (977-deep chains, ~30-40us) replaced by
//      bhist2 (LDS hist -> plain stores, structure = proven bscatter3
//      pass-1) + rowsum (block-per-bucket LDS tree reduce -> bcount).
//      ALL ELSE BYTE-IDENTICAL to proven R16 (bscatter3 with bcur atomics,
//      bcsr, gathers). hist lives in slot0 slack (3.2MB >= 1.15MB,
//      lifetimes disjoint) -> workspace footprint unchanged.

#ifndef EMB
#define EMB 64
#endif
#define BSHIFT 7                 // 128 nodes per bucket
#define BNODES (1 << BSHIFT)
#define NBMAX 1280               // LDS histogram capacity
#define CCAP 4800                // LDS pair-staging capacity per bucket
#define CH 16384                 // edges per chunk (bhist2/bscatter3)
#define STH 1024                 // threads per block (bhist2/bscatter3)

typedef unsigned int uint;
typedef unsigned short ushort;

static __device__ __forceinline__ ushort f2h(float f) {
    __half h = __float2half(f);
    return *(ushort*)&h;
}

// u = two packed fp16; accumulate {lo,hi} into aL,aH (R12-proven form).
static __device__ __forceinline__ void acc2h(uint u, float& aL, float& aH) {
    __half2 h = *(__half2*)&u;
    float2 f = __half22float2(h);
    aL += f.x;
    aH += f.y;
}

static __device__ __forceinline__ float2 h2f2(uint u) {
    __half2 h = *(__half2*)&u;
    return __half22float2(h);
}

// ---- setup: dtype detect + zero bucket counters + zero dummy rows ----
__global__ void lgcn_setup_kernel(const int* __restrict__ ei,
                                  int* __restrict__ flag,
                                  int* __restrict__ bcount,
                                  int* __restrict__ bcur,
                                  ushort* __restrict__ z0,
                                  ushort* __restrict__ z1,
                                  ushort* __restrict__ z2,
                                  int NB, int n_elems) {
    __shared__ int any_nz;
    int t = threadIdx.x;
    if (t == 0) any_nz = 0;
    __syncthreads();
    if (t < 128 && ei[2 * t + 1] != 0) atomicOr(&any_nz, 1);
    for (int i = t; i < NB; i += 256) { bcount[i] = 0; bcur[i] = 0; }
    if (t < EMB) {
        z0[n_elems + t] = 0;
        z1[n_elems + t] = 0;
        z2[n_elems + t] = 0;
    }
    __syncthreads();
    if (t == 0) *flag = (any_nz == 0) ? 1 : 0;
}

static __device__ __forceinline__ int load_idx(const int* __restrict__ ei,
                                               long long elem, int is64,
                                               int n_nodes) {
    int v = is64 ? ei[elem << 1] : ei[elem];
    return min(max(v, 0), n_nodes - 1);
}

// ---- build step 1: per-chunk bucket histogram, NO global atomics ----
// Structure = proven bscatter3 pass-1; output = plain stores.
__global__ void __launch_bounds__(STH)
lgcn_bhist2_kernel(const int* __restrict__ ei,
                   const int* __restrict__ flag,
                   int* __restrict__ hist,
                   int n_edges, int n_nodes, int NB, int nblk) {
    __shared__ int lcount[NBMAX];
    int t = threadIdx.x;
    int blk = blockIdx.x;
    int is64 = *flag;
    long long base = (long long)blk * CH;
    for (int i = t; i < NB; i += STH) lcount[i] = 0;
    __syncthreads();
    for (int k = t; k < CH; k += STH) {
        long long e = base + k;
        if (e < n_edges) {
            int c = load_idx(ei, (long long)n_edges + e, is64, n_nodes);
            atomicAdd(&lcount[c >> BSHIFT], 1);   // LDS only
        }
    }
    __syncthreads();
    for (int i = t; i < NB; i += STH)
        hist[(size_t)i * nblk + blk] = lcount[i];
}

// ---- build step 1b: per-bucket row sum: hist row -> bcount[b] ----
__global__ void lgcn_rowsum_kernel(const int* __restrict__ hist,
                                   int* __restrict__ bcount,
                                   int nblk) {
    __shared__ int red[256];
    int b = blockIdx.x;
    int t = threadIdx.x;            // 256 threads
    const int* row = hist + (size_t)b * nblk;
    int s = 0;
    for (int j = t; j < nblk; j += 256) s += row[j];
    red[t] = s;
    __syncthreads();
    for (int off = 128; off > 0; off >>= 1) {
        if (t < off) red[t] += red[t + off];
        __syncthreads();
    }
    if (t == 0) bcount[b] = red[0];
}

// ---- build step 2: exclusive scan of bucket counts (single block) ----
__global__ void lgcn_bscan_kernel(const int* __restrict__ bcount,
                                  int* __restrict__ bucketBase,
                                  int* __restrict__ offsets,
                                  int NB, int n_nodes) {
    __shared__ int tsum[256];
    int t = threadIdx.x;
    int K = (NB + 255) / 256;
    int base = t * K;
    int s = 0;
    for (int k = 0; k < K; ++k) {
        int i = base + k;
        if (i < NB) s += bcount[i];
    }
    tsum[t] = s;
    __syncthreads();
    for (int off = 1; off < 256; off <<= 1) {
        int x = (t >= off) ? tsum[t - off] : 0;
        __syncthreads();
        tsum[t] += x;
        __syncthreads();
    }
    int run = tsum[t] - s;
    for (int k = 0; k < K; ++k) {
        int i = base + k;
        if (i < NB) { bucketBase[i] = run; run += bcount[i]; }
    }
    if (t == 255) {
        bucketBase[NB] = tsum[255];
        offsets[n_nodes] = tsum[255];
    }
}

// ---- build step 3: block-aggregated pair scatter, LDS-staged (R12) ----
__global__ void __launch_bounds__(STH)
lgcn_bscatter3_kernel(const int* __restrict__ ei,
                      const int* __restrict__ flag,
                      const int* __restrict__ bucketBase,
                      int* __restrict__ bcur,
                      uint* __restrict__ pairs,
                      int n_edges, int n_nodes, int NB) {
    __shared__ int lcount[NBMAX];   // histogram, then staging cursor
    __shared__ int lloc[NBMAX];     // local staging base per bucket
    __shared__ int ldelta[NBMAX];   // global_run_base - local_base
    __shared__ int tsum[STH];
    __shared__ int ltot;
    __shared__ uint stage[CH];      // 64 KB pair staging
    __shared__ ushort stageb[CH];   // 32 KB bucket id per staged pair
    int t = threadIdx.x;
    int is64 = *flag;
    long long base = (long long)blockIdx.x * CH;
    for (int i = t; i < NB; i += STH) lcount[i] = 0;
    __syncthreads();
    // pass 1: local histogram of target buckets
    for (int k = t; k < CH; k += STH) {
        long long e = base + k;
        if (e < n_edges) {
            int c = load_idx(ei, (long long)n_edges + e, is64, n_nodes);
            atomicAdd(&lcount[c >> BSHIFT], 1);
        }
    }
    __syncthreads();
    // local exclusive scan lcount -> lloc (staging layout)
    {
        int K = (NB + STH - 1) / STH;
        int cbase = t * K;
        int s = 0;
        for (int k = 0; k < K; ++k) {
            int i = cbase + k;
            if (i < NB) s += lcount[i];
        }
        tsum[t] = s;
        __syncthreads();
        for (int off = 1; off < STH; off <<= 1) {
            int x = (t >= off) ? tsum[t - off] : 0;
            __syncthreads();
            tsum[t] += x;
            __syncthreads();
        }
        int run = tsum[t] - s;
        for (int k = 0; k < K; ++k) {
            int i = cbase + k;
            if (i < NB) { lloc[i] = run; run += lcount[i]; }
        }
        if (t == STH - 1) ltot = tsum[t];
    }
    __syncthreads();
    // reservation: one global atomic per non-empty bucket
    for (int i = t; i < NB; i += STH) {
        int cnt = lcount[i];
        ldelta[i] = cnt ? (bucketBase[i] + atomicAdd(&bcur[i], cnt) - lloc[i]) : 0;
        lcount[i] = 0;   // reuse as staging cursor
    }
    __syncthreads();
    // pass 2: stage pairs grouped by bucket in LDS
    for (int k = t; k < CH; k += STH) {
        long long e = base + k;
        if (e < n_edges) {
            int r = load_idx(ei, e, is64, n_nodes);
            int c = load_idx(ei, (long long)n_edges + e, is64, n_nodes);
            int b = c >> BSHIFT;
            int pos = lloc[b] + atomicAdd(&lcount[b], 1);
            stage[pos] = ((uint)r << BSHIFT) | (uint)(c & (BNODES - 1));
            stageb[pos] = (ushort)b;
        }
    }
    __syncthreads();
    // pass 3: coalesced run-contiguous global writes
    int tot = ltot;
    for (int k = t; k < tot; k += STH) {
        pairs[ldelta[stageb[k]] + k] = stage[k];
    }
}

// ---- build step 4: per-bucket CSR finalize + fused z0 init ----
__global__ void lgcn_bcsr_kernel(const uint* __restrict__ pairs,
                                 const int* __restrict__ bucketBase,
                                 const float* __restrict__ user_w,
                                 const float* __restrict__ item_w,
                                 int* __restrict__ offsets,
                                 int* __restrict__ csr_rows,
                                 float* __restrict__ dis,
                                 ushort* __restrict__ z0,
                                 int n_user_elems, int n_nodes) {
    __shared__ int deg[BNODES];
    __shared__ int tmp[BNODES];
    __shared__ int loffx[BNODES];
    __shared__ int cur[BNODES];
    __shared__ float disL[BNODES];
    __shared__ uint lp[CCAP];
    int b = blockIdx.x;
    int t = threadIdx.x;            // 256 threads
    int nodeStart = b << BSHIFT;
    int base = bucketBase[b];
    int span = bucketBase[b + 1] - base;
    bool fits = (span <= CCAP);
    if (t < BNODES) deg[t] = 0;
    __syncthreads();
    for (int i = t; i < span; i += 256) {
        uint p = pairs[base + i];
        if (fits) lp[i] = p;
        atomicAdd(&deg[p & (BNODES - 1)], 1);
    }
    __syncthreads();
    if (t < BNODES) tmp[t] = deg[t];
    __syncthreads();
    for (int off = 1; off < BNODES; off <<= 1) {
        int x = (t < BNODES && t >= off) ? tmp[t - off] : 0;
        __syncthreads();
        if (t < BNODES) tmp[t] += x;
        __syncthreads();
    }
    if (t < BNODES) {
        int excl = tmp[t] - deg[t];
        loffx[t] = excl;
        cur[t] = 0;
        float d = (deg[t] > 0) ? rsqrtf((float)deg[t]) : 0.0f;
        disL[t] = d;
        int node = nodeStart + t;
        if (node < n_nodes) {
            offsets[node] = base + excl;
            dis[node] = d;
        }
    }
    __syncthreads();
    for (int i = t; i < span; i += 256) {
        uint p = fits ? lp[i] : pairs[base + i];
        int cl = (int)(p & (BNODES - 1));
        int pos = loffx[cl] + atomicAdd(&cur[cl], 1);
        csr_rows[base + pos] = (int)(p >> BSHIFT);
    }
    // fused init: z0 rows for this bucket's nodes, z0 = fp16(dis * x)
    int eBase = nodeStart << 6;               // first element of this bucket
    for (int e4 = t; e4 < (BNODES << 4); e4 += 256) {   // float4 granules
        int e = e4 << 2;
        int node = nodeStart + (e >> 6);
        if (node < n_nodes) {
            int gi = eBase + e;
            float4 v = (gi < n_user_elems)
                ? *(const float4*)(user_w + gi)
                : *(const float4*)(item_w + (gi - n_user_elems));
            float d = disL[e >> 6];
            ushort4 o;
            o.x = f2h(d * v.x); o.y = f2h(d * v.y);
            o.z = f2h(d * v.z); o.w = f2h(d * v.w);
            *(ushort4*)(z0 + gi) = o;
        }
    }
}

// gather: one wave per node; 8 lanes per edge (uint4 = 16B per lane).
// R12-proven body: scalar acc2h into a[8]; up to 64 adjacency entries in
// one coalesced csr read; all row gathers back-to-back.
// FUSE (layer 3): epilogue computes out = 0.25*(x + inv*(z1+z2) + dc*sum).
template <bool FUSE>
__global__ void lgcn_gather_kernel(const int* __restrict__ csr_rows,
                                   const int* __restrict__ offsets,
                                   const float* __restrict__ dis,
                                   const ushort* __restrict__ zin,
                                   ushort* __restrict__ zout,
                                   const ushort* __restrict__ zprev,
                                   const float* __restrict__ user_w,
                                   const float* __restrict__ item_w,
                                   float* __restrict__ out,
                                   int n_user_elems, int n_nodes) {
    long long tid = (long long)blockIdx.x * blockDim.x + threadIdx.x;
    int c    = (int)(tid >> 6);
    int lane = threadIdx.x & 63;
    int oct  = lane >> 3;   // edge slot 0..7 within a group
    int o8   = lane & 7;    // which 16B chunk of the 128B row
    if (c >= n_nodes) return;
    int beg = offsets[c];
    int end = offsets[c + 1];
    int deg = end - beg;
    float a[8];
    #pragma unroll
    for (int k = 0; k < 8; ++k) a[k] = 0.0f;

    if (deg > 0) {
        int n1 = deg < 64 ? deg : 64;
        int ng = (n1 + 7) >> 3;        // active groups (wave-uniform)
        int rr[8];
        #pragma unroll
        for (int g = 0; g < 8; ++g) {
            int s = g * 8 + oct;
            if (g < ng) {
                int r = csr_rows[beg + (s < n1 ? s : 0)];
                rr[g] = (s < n1) ? r : n_nodes;      // zero row for tail
            } else {
                rr[g] = n_nodes;
            }
        }
        uint4 q[8];
        #pragma unroll
        for (int g = 0; g < 8; ++g)
            if (g < ng)
                q[g] = *(const uint4*)(zin + (size_t)rr[g] * EMB + o8 * 8);
        #pragma unroll
        for (int g = 0; g < 8; ++g) {
            if (g < ng) {
                acc2h(q[g].x, a[0], a[1]);
                acc2h(q[g].y, a[2], a[3]);
                acc2h(q[g].z, a[4], a[5]);
                acc2h(q[g].w, a[6], a[7]);
            }
        }
        // rare tail: deg > 64
        for (int j = beg + 64; j < end; j += 16) {
            int j0 = j + oct;
            int j1 = j + 8 + oct;
            bool v0 = j0 < end;
            bool v1 = j1 < end;
            int r0 = csr_rows[v0 ? j0 : beg]; r0 = v0 ? r0 : n_nodes;
            int r1 = csr_rows[v1 ? j1 : beg]; r1 = v1 ? r1 : n_nodes;
            uint4 q0 = *(const uint4*)(zin + (size_t)r0 * EMB + o8 * 8);
            uint4 q1 = *(const uint4*)(zin + (size_t)r1 * EMB + o8 * 8);
            acc2h(q0.x, a[0], a[1]);
            acc2h(q0.y, a[2], a[3]);
            acc2h(q0.z, a[4], a[5]);
            acc2h(q0.w, a[6], a[7]);
            acc2h(q1.x, a[0], a[1]);
            acc2h(q1.y, a[2], a[3]);
            acc2h(q1.z, a[4], a[5]);
            acc2h(q1.w, a[6], a[7]);
        }
    }

    #pragma unroll
    for (int k = 0; k < 8; ++k) {
        a[k] += __shfl_xor(a[k], 8, 64);
        a[k] += __shfl_xor(a[k], 16, 64);
        a[k] += __shfl_xor(a[k], 32, 64);
    }

    if (oct == 0) {   // lanes 0..7; lane l holds dims [8*l, 8*l+8)
        float dc = dis[c];
        size_t fo = (size_t)c * EMB + o8 * 8;
        if (!FUSE) {
            float s2 = dc * dc;               // z_new = dis^2 * sum
            uint4 v;
            v.x = ((uint)f2h(s2 * a[1]) << 16) | f2h(s2 * a[0]);
            v.y = ((uint)f2h(s2 * a[3]) << 16) | f2h(s2 * a[2]);
            v.z = ((uint)f2h(s2 * a[5]) << 16) | f2h(s2 * a[4]);
            v.w = ((uint)f2h(s2 * a[7]) << 16) | f2h(s2 * a[6]);
            *(uint4*)(zout + fo) = v;
        } else {
            // out = 0.25*(x + inv*(z1+z2) + dc*sum); inv = 1/dc (0 if deg=0)
            float inv = (dc > 0.0f) ? 1.0f / dc : 0.0f;
            uint4 v1 = *(const uint4*)(zprev + fo);
            uint4 v2 = *(const uint4*)(zin + fo);
            float4 x0, x1;
            if ((int)fo < n_user_elems) {
                x0 = *(const float4*)(user_w + fo);
                x1 = *(const float4*)(user_w + fo + 4);
            } else {
                size_t j = fo - n_user_elems;
                x0 = *(const float4*)(item_w + j);
                x1 = *(const float4*)(item_w + j + 4);
            }
            float2 p, q;
            float4 o0, o1;
            p = h2f2(v1.x); q = h2f2(v2.x);
            o0.x = 0.25f * (x0.x + inv * (p.x + q.x) + dc * a[0]);
            o0.y = 0.25f * (x0.y + inv * (p.y + q.y) + dc * a[1]);
            p = h2f2(v1.y); q = h2f2(v2.y);
            o0.z = 0.25f * (x0.z + inv * (p.x + q.x) + dc * a[2]);
            o0.w = 0.25f * (x0.w + inv * (p.y + q.y) + dc * a[3]);
            p = h2f2(v1.z); q = h2f2(v2.z);
            o1.x = 0.25f * (x1.x + inv * (p.x + q.x) + dc * a[4]);
            o1.y = 0.25f * (x1.y + inv * (p.y + q.y) + dc * a[5]);
            p = h2f2(v1.w); q = h2f2(v2.w);
            o1.z = 0.25f * (x1.z + inv * (p.x + q.x) + dc * a[6]);
            o1.w = 0.25f * (x1.w + inv * (p.y + q.y) + dc * a[7]);
            *(float4*)(out + fo) = o0;
            *(float4*)(out + fo + 4) = o1;
        }
    }
}

extern "C" void kernel_launch(void* const* d_in, const int* in_sizes, int n_in,
                              void* d_out, int out_size, void* d_ws, size_t ws_size,
                              hipStream_t stream) {
    // ---- role assignment by element count ----
    int ie = 0, iu = 1, ii = 2;
    {
        long long s[3] = { in_sizes[0], in_sizes[1], in_sizes[2] };
        ie = 0;
        if (s[1] > s[ie]) ie = 1;
        if (s[2] > s[ie]) ie = 2;
        int rest[2], k = 0;
        for (int j = 0; j < 3; ++j) if (j != ie) rest[k++] = j;
        if (s[rest[0]] >= s[rest[1]]) { iu = rest[0]; ii = rest[1]; }
        else                          { iu = rest[1]; ii = rest[0]; }
    }
    const int*   edge_index = (const int*)d_in[ie];
    const float* user_w     = (const float*)d_in[iu];
    const float* item_w     = (const float*)d_in[ii];
    float* out = (float*)d_out;

    const int n_edges = in_sizes[ie] / 2;
    const int n_users = in_sizes[iu] / EMB;
    const int n_items = in_sizes[ii] / EMB;
    const int n_nodes = n_users + n_items;
    const int n_elems = n_nodes * EMB;
    const int NB = (n_nodes + BNODES - 1) / BNODES;   // 1172
    const int nblk = (n_edges + CH - 1) / CH;         // 245

    // ---- workspace carve (byte-identical footprint to proven R16) ----
    // fp16 state buffers each have one extra zero row at node index n_nodes.
    // hist lives in slot0's slack after pairs' 16MB (3.2MB slack >= 1.15MB
    // needed; lifetimes disjoint). Fallback appends only if slack short.
    auto align_up = [](size_t x) { return (x + 1023) & ~(size_t)1023; };
    char* w = (char*)d_ws;
    int*   flag       = (int*)w; w += 1024;
    int*   bcount     = (int*)w; w += align_up((size_t)NB * sizeof(int));
    int*   bucketBase = (int*)w; w += align_up(((size_t)NB + 1) * sizeof(int));
    int*   bcur       = (int*)w; w += align_up((size_t)NB * sizeof(int));
    int*   offsets    = (int*)w; w += align_up(((size_t)n_nodes + 1) * sizeof(int));
    float* dis        = (float*)w; w += align_up((size_t)n_nodes * sizeof(float));
    int*   csr_rows   = (int*)w; w += align_up((size_t)n_edges * sizeof(int));
    size_t u_bytes = align_up(((size_t)n_elems + EMB) * sizeof(ushort));
    size_t p_bytes = align_up((size_t)n_edges * sizeof(uint));
    size_t slot0   = (u_bytes > p_bytes ? u_bytes : p_bytes);
    size_t h_bytes = align_up((size_t)NB * nblk * sizeof(int));
    char*  slot0p = w;
    uint*  pairs  = (uint*)slot0p; w += slot0;
    ushort* z0    = (ushort*)w; w += u_bytes;
    ushort* z1    = (ushort*)w; w += u_bytes;
    ushort* z2    = (ushort*)w; w += u_bytes;
    int* hist;
    if (slot0 >= p_bytes + h_bytes) {
        hist = (int*)(slot0p + p_bytes);
    } else {
        hist = (int*)w; w += h_bytes;
    }

    // 0) setup: dtype detect + zero counters + zero dummy rows
    lgcn_setup_kernel<<<1, 256, 0, stream>>>(edge_index, flag, bcount, bcur,
                                             z0, z1, z2, NB, n_elems);

    // 1) atomic-free histogram -> row sum -> bucket scan -> staged scatter
    //    (proven bscatter3) -> bucket CSR(+init)
    lgcn_bhist2_kernel<<<nblk, STH, 0, stream>>>(
        edge_index, flag, hist, n_edges, n_nodes, NB, nblk);
    lgcn_rowsum_kernel<<<NB, 256, 0, stream>>>(hist, bcount, nblk);
    lgcn_bscan_kernel<<<1, 256, 0, stream>>>(bcount, bucketBase, offsets, NB, n_nodes);
    lgcn_bscatter3_kernel<<<nblk, STH, 0, stream>>>(
        edge_index, flag, bucketBase, bcur, pairs, n_edges, n_nodes, NB);
    lgcn_bcsr_kernel<<<NB, 256, 0, stream>>>(
        pairs, bucketBase, user_w, item_w, offsets, csr_rows, dis, z0,
        n_users * EMB, n_nodes);

    // 2) 3 pull layers: z0 -> z1 -> z2 -> (fused) out
    {
        const int BLK = 256;   // 4 nodes/block
        long long n_thr = (long long)n_nodes * 64;
        int gW = (int)((n_thr + BLK - 1) / BLK);
        lgcn_gather_kernel<false><<<gW, BLK, 0, stream>>>(
            csr_rows, offsets, dis, z0, z1,
            nullptr, nullptr, nullptr, nullptr, 0, n_nodes);
        lgcn_gather_kernel<false><<<gW, BLK, 0, stream>>>(
            csr_rows, offsets, dis, z1, z2,
            nullptr, nullptr, nullptr, nullptr, 0, n_nodes);
        lgcn_gather_kernel<true><<<gW, BLK, 0, stream>>>(
            csr_rows, offsets, dis, z2, nullptr,
            z1, user_w, item_w, out, n_users * EMB, n_nodes);
    }
}

// Round 12
// 407.852 us; speedup vs baseline: 1.1137x; 1.0231x over previous
//
#include <hip/hip_runtime.h>
#include <hip/hip_fp16.h>

// LightGCN on MI355X — atomic-free bucket build + batched-MLP gather,
// deferred-total fp16 pipeline.
//
// R9:  bscatter 1024thr/CH=16384 (566->512).
// R10: batched 64-entry adjacency read + dis folded into state (512->481).
// R11: total deferred out of gathers; fp16 state; final pass (481->459).
// R12: bscatter pairs staged in LDS grouped by bucket (459->434).
// R13: FUSE final into g3 (WIN). R14/R15: gather 86us/259MB = steady state
//      (L2-miss traffic to L3; random-128B fabric regime). R16: NT revert
//      (454->422).
// R17/R18: full atomic-free build died at container level (2x). R19
//      re-landed bhist2+rowsum+hist-aliasing WITHOUT bscatter4: ran clean,
//      422->417. Those pieces + slack-aliasing exonerated.
// R20: re-land bscatter4 (deterministic scatter) on the proven R19 base:
//      no pass-1 edge re-read (hist column instead, -32MB), no bcur
//      atomics (ldelta from runbase). runbase joins hist in slot0 slack
//      (16MB pairs + 2.3MB <= 19.2MB, lifetimes disjoint). Everything
//      else byte-identical to R19. If container dies: 3 strikes ->
//      bscatter4 condemned, revert permanently.

#ifndef EMB
#define EMB 64
#endif
#define BSHIFT 7                 // 128 nodes per bucket
#define BNODES (1 << BSHIFT)
#define NBMAX 1280               // LDS histogram capacity
#define CCAP 4800                // LDS pair-staging capacity per bucket
#define CH 16384                 // edges per chunk (bhist2/bscatter4)
#define STH 1024                 // threads per block (bhist2/bscatter4)

typedef unsigned int uint;
typedef unsigned short ushort;

static __device__ __forceinline__ ushort f2h(float f) {
    __half h = __float2half(f);
    return *(ushort*)&h;
}

// u = two packed fp16; accumulate {lo,hi} into aL,aH (R12-proven form).
static __device__ __forceinline__ void acc2h(uint u, float& aL, float& aH) {
    __half2 h = *(__half2*)&u;
    float2 f = __half22float2(h);
    aL += f.x;
    aH += f.y;
}

static __device__ __forceinline__ float2 h2f2(uint u) {
    __half2 h = *(__half2*)&u;
    return __half22float2(h);
}

// ---- setup: dtype detect + zero dummy rows ----
__global__ void lgcn_setup_kernel(const int* __restrict__ ei,
                                  int* __restrict__ flag,
                                  ushort* __restrict__ z0,
                                  ushort* __restrict__ z1,
                                  ushort* __restrict__ z2,
                                  int n_elems) {
    __shared__ int any_nz;
    int t = threadIdx.x;
    if (t == 0) any_nz = 0;
    __syncthreads();
    if (t < 128 && ei[2 * t + 1] != 0) atomicOr(&any_nz, 1);
    if (t < EMB) {
        z0[n_elems + t] = 0;
        z1[n_elems + t] = 0;
        z2[n_elems + t] = 0;
    }
    __syncthreads();
    if (t == 0) *flag = (any_nz == 0) ? 1 : 0;
}

static __device__ __forceinline__ int load_idx(const int* __restrict__ ei,
                                               long long elem, int is64,
                                               int n_nodes) {
    int v = is64 ? ei[elem << 1] : ei[elem];
    return min(max(v, 0), n_nodes - 1);
}

// ---- build step 1: per-chunk bucket histogram, NO global atomics ----
__global__ void __launch_bounds__(STH)
lgcn_bhist2_kernel(const int* __restrict__ ei,
                   const int* __restrict__ flag,
                   int* __restrict__ hist,
                   int n_edges, int n_nodes, int NB, int nblk) {
    __shared__ int lcount[NBMAX];
    int t = threadIdx.x;
    int blk = blockIdx.x;
    int is64 = *flag;
    long long base = (long long)blk * CH;
    for (int i = t; i < NB; i += STH) lcount[i] = 0;
    __syncthreads();
    for (int k = t; k < CH; k += STH) {
        long long e = base + k;
        if (e < n_edges) {
            int c = load_idx(ei, (long long)n_edges + e, is64, n_nodes);
            atomicAdd(&lcount[c >> BSHIFT], 1);   // LDS only
        }
    }
    __syncthreads();
    for (int i = t; i < NB; i += STH)
        hist[(size_t)i * nblk + blk] = lcount[i];
}

// ---- build step 2a: per-bucket row scan: hist row -> runbase row, total ----
__global__ void lgcn_rowscan_kernel(const int* __restrict__ hist,
                                    int* __restrict__ runbase,
                                    int* __restrict__ bcount,
                                    int nblk) {
    __shared__ int tsum[256];
    int b = blockIdx.x;
    int t = threadIdx.x;            // 256 threads
    const int* row = hist + (size_t)b * nblk;
    int* orow = runbase + (size_t)b * nblk;
    int v = (t < nblk) ? row[t] : 0;    // nblk=245 <= 256
    tsum[t] = v;
    __syncthreads();
    for (int off = 1; off < 256; off <<= 1) {
        int x = (t >= off) ? tsum[t - off] : 0;
        __syncthreads();
        tsum[t] += x;
        __syncthreads();
    }
    if (t < nblk) orow[t] = tsum[t] - v;   // exclusive
    if (t == 255) bcount[b] = tsum[255];
}

// ---- build step 2b: exclusive scan of bucket counts (single block) ----
__global__ void lgcn_bscan_kernel(const int* __restrict__ bcount,
                                  int* __restrict__ bucketBase,
                                  int* __restrict__ offsets,
                                  int NB, int n_nodes) {
    __shared__ int tsum[256];
    int t = threadIdx.x;
    int K = (NB + 255) / 256;
    int base = t * K;
    int s = 0;
    for (int k = 0; k < K; ++k) {
        int i = base + k;
        if (i < NB) s += bcount[i];
    }
    tsum[t] = s;
    __syncthreads();
    for (int off = 1; off < 256; off <<= 1) {
        int x = (t >= off) ? tsum[t - off] : 0;
        __syncthreads();
        tsum[t] += x;
        __syncthreads();
    }
    int run = tsum[t] - s;
    for (int k = 0; k < K; ++k) {
        int i = base + k;
        if (i < NB) { bucketBase[i] = run; run += bcount[i]; }
    }
    if (t == 255) {
        bucketBase[NB] = tsum[255];
        offsets[n_nodes] = tsum[255];
    }
}

// ---- build step 3: deterministic LDS-staged pair scatter ----
// hist column replaces pass-1 edge read; ldelta from runbase (no atomics);
// stage + run-contiguous write as proven R12/bscatter3.
__global__ void __launch_bounds__(STH)
lgcn_bscatter4_kernel(const int* __restrict__ ei,
                      const int* __restrict__ flag,
                      const int* __restrict__ bucketBase,
                      const int* __restrict__ hist,
                      const int* __restrict__ runbase,
                      uint* __restrict__ pairs,
                      int n_edges, int n_nodes, int NB, int nblk) {
    __shared__ int lcount[NBMAX];   // counts, then staging cursor
    __shared__ int lloc[NBMAX];     // local staging base per bucket
    __shared__ int ldelta[NBMAX];   // global_run_base - local_base
    __shared__ int tsum[STH];
    __shared__ int ltot;
    __shared__ uint stage[CH];      // 64 KB pair staging
    __shared__ ushort stageb[CH];   // 32 KB bucket id per staged pair
    int t = threadIdx.x;
    int blk = blockIdx.x;
    int is64 = *flag;
    long long base = (long long)blk * CH;
    // load this chunk's histogram column
    for (int i = t; i < NB; i += STH)
        lcount[i] = hist[(size_t)i * nblk + blk];
    __syncthreads();
    // local exclusive scan lcount -> lloc (staging layout)
    {
        int K = (NB + STH - 1) / STH;
        int cbase = t * K;
        int s = 0;
        for (int k = 0; k < K; ++k) {
            int i = cbase + k;
            if (i < NB) s += lcount[i];
        }
        tsum[t] = s;
        __syncthreads();
        for (int off = 1; off < STH; off <<= 1) {
            int x = (t >= off) ? tsum[t - off] : 0;
            __syncthreads();
            tsum[t] += x;
            __syncthreads();
        }
        int run = tsum[t] - s;
        for (int k = 0; k < K; ++k) {
            int i = cbase + k;
            if (i < NB) { lloc[i] = run; run += lcount[i]; }
        }
        if (t == STH - 1) ltot = tsum[t];
    }
    __syncthreads();
    // deterministic reservation (no atomics)
    for (int i = t; i < NB; i += STH) {
        ldelta[i] = bucketBase[i] + runbase[(size_t)i * nblk + blk] - lloc[i];
        lcount[i] = 0;   // reuse as staging cursor
    }
    __syncthreads();
    // stage pairs grouped by bucket in LDS
    for (int k = t; k < CH; k += STH) {
        long long e = base + k;
        if (e < n_edges) {
            int r = load_idx(ei, e, is64, n_nodes);
            int c = load_idx(ei, (long long)n_edges + e, is64, n_nodes);
            int b = c >> BSHIFT;
            int pos = lloc[b] + atomicAdd(&lcount[b], 1);   // LDS only
            stage[pos] = ((uint)r << BSHIFT) | (uint)(c & (BNODES - 1));
            stageb[pos] = (ushort)b;
        }
    }
    __syncthreads();
    // coalesced run-contiguous global writes
    int tot = ltot;
    for (int k = t; k < tot; k += STH) {
        pairs[ldelta[stageb[k]] + k] = stage[k];
    }
}

// ---- build step 4: per-bucket CSR finalize + fused z0 init ----
__global__ void lgcn_bcsr_kernel(const uint* __restrict__ pairs,
                                 const int* __restrict__ bucketBase,
                                 const float* __restrict__ user_w,
                                 const float* __restrict__ item_w,
                                 int* __restrict__ offsets,
                                 int* __restrict__ csr_rows,
                                 float* __restrict__ dis,
                                 ushort* __restrict__ z0,
                                 int n_user_elems, int n_nodes) {
    __shared__ int deg[BNODES];
    __shared__ int tmp[BNODES];
    __shared__ int loffx[BNODES];
    __shared__ int cur[BNODES];
    __shared__ float disL[BNODES];
    __shared__ uint lp[CCAP];
    int b = blockIdx.x;
    int t = threadIdx.x;            // 256 threads
    int nodeStart = b << BSHIFT;
    int base = bucketBase[b];
    int span = bucketBase[b + 1] - base;
    bool fits = (span <= CCAP);
    if (t < BNODES) deg[t] = 0;
    __syncthreads();
    for (int i = t; i < span; i += 256) {
        uint p = pairs[base + i];
        if (fits) lp[i] = p;
        atomicAdd(&deg[p & (BNODES - 1)], 1);
    }
    __syncthreads();
    if (t < BNODES) tmp[t] = deg[t];
    __syncthreads();
    for (int off = 1; off < BNODES; off <<= 1) {
        int x = (t < BNODES && t >= off) ? tmp[t - off] : 0;
        __syncthreads();
        if (t < BNODES) tmp[t] += x;
        __syncthreads();
    }
    if (t < BNODES) {
        int excl = tmp[t] - deg[t];
        loffx[t] = excl;
        cur[t] = 0;
        float d = (deg[t] > 0) ? rsqrtf((float)deg[t]) : 0.0f;
        disL[t] = d;
        int node = nodeStart + t;
        if (node < n_nodes) {
            offsets[node] = base + excl;
            dis[node] = d;
        }
    }
    __syncthreads();
    for (int i = t; i < span; i += 256) {
        uint p = fits ? lp[i] : pairs[base + i];
        int cl = (int)(p & (BNODES - 1));
        int pos = loffx[cl] + atomicAdd(&cur[cl], 1);
        csr_rows[base + pos] = (int)(p >> BSHIFT);
    }
    // fused init: z0 rows for this bucket's nodes, z0 = fp16(dis * x)
    int eBase = nodeStart << 6;               // first element of this bucket
    for (int e4 = t; e4 < (BNODES << 4); e4 += 256) {   // float4 granules
        int e = e4 << 2;
        int node = nodeStart + (e >> 6);
        if (node < n_nodes) {
            int gi = eBase + e;
            float4 v = (gi < n_user_elems)
                ? *(const float4*)(user_w + gi)
                : *(const float4*)(item_w + (gi - n_user_elems));
            float d = disL[e >> 6];
            ushort4 o;
            o.x = f2h(d * v.x); o.y = f2h(d * v.y);
            o.z = f2h(d * v.z); o.w = f2h(d * v.w);
            *(ushort4*)(z0 + gi) = o;
        }
    }
}

// gather: one wave per node; 8 lanes per edge (uint4 = 16B per lane).
// R12-proven body: scalar acc2h into a[8]; up to 64 adjacency entries in
// one coalesced csr read; all row gathers back-to-back.
// FUSE (layer 3): epilogue computes out = 0.25*(x + inv*(z1+z2) + dc*sum).
template <bool FUSE>
__global__ void lgcn_gather_kernel(const int* __restrict__ csr_rows,
                                   const int* __restrict__ offsets,
                                   const float* __restrict__ dis,
                                   const ushort* __restrict__ zin,
                                   ushort* __restrict__ zout,
                                   const ushort* __restrict__ zprev,
                                   const float* __restrict__ user_w,
                                   const float* __restrict__ item_w,
                                   float* __restrict__ out,
                                   int n_user_elems, int n_nodes) {
    long long tid = (long long)blockIdx.x * blockDim.x + threadIdx.x;
    int c    = (int)(tid >> 6);
    int lane = threadIdx.x & 63;
    int oct  = lane >> 3;   // edge slot 0..7 within a group
    int o8   = lane & 7;    // which 16B chunk of the 128B row
    if (c >= n_nodes) return;
    int beg = offsets[c];
    int end = offsets[c + 1];
    int deg = end - beg;
    float a[8];
    #pragma unroll
    for (int k = 0; k < 8; ++k) a[k] = 0.0f;

    if (deg > 0) {
        int n1 = deg < 64 ? deg : 64;
        int ng = (n1 + 7) >> 3;        // active groups (wave-uniform)
        int rr[8];
        #pragma unroll
        for (int g = 0; g < 8; ++g) {
            int s = g * 8 + oct;
            if (g < ng) {
                int r = csr_rows[beg + (s < n1 ? s : 0)];
                rr[g] = (s < n1) ? r : n_nodes;      // zero row for tail
            } else {
                rr[g] = n_nodes;
            }
        }
        uint4 q[8];
        #pragma unroll
        for (int g = 0; g < 8; ++g)
            if (g < ng)
                q[g] = *(const uint4*)(zin + (size_t)rr[g] * EMB + o8 * 8);
        #pragma unroll
        for (int g = 0; g < 8; ++g) {
            if (g < ng) {
                acc2h(q[g].x, a[0], a[1]);
                acc2h(q[g].y, a[2], a[3]);
                acc2h(q[g].z, a[4], a[5]);
                acc2h(q[g].w, a[6], a[7]);
            }
        }
        // rare tail: deg > 64
        for (int j = beg + 64; j < end; j += 16) {
            int j0 = j + oct;
            int j1 = j + 8 + oct;
            bool v0 = j0 < end;
            bool v1 = j1 < end;
            int r0 = csr_rows[v0 ? j0 : beg]; r0 = v0 ? r0 : n_nodes;
            int r1 = csr_rows[v1 ? j1 : beg]; r1 = v1 ? r1 : n_nodes;
            uint4 q0 = *(const uint4*)(zin + (size_t)r0 * EMB + o8 * 8);
            uint4 q1 = *(const uint4*)(zin + (size_t)r1 * EMB + o8 * 8);
            acc2h(q0.x, a[0], a[1]);
            acc2h(q0.y, a[2], a[3]);
            acc2h(q0.z, a[4], a[5]);
            acc2h(q0.w, a[6], a[7]);
            acc2h(q1.x, a[0], a[1]);
            acc2h(q1.y, a[2], a[3]);
            acc2h(q1.z, a[4], a[5]);
            acc2h(q1.w, a[6], a[7]);
        }
    }

    #pragma unroll
    for (int k = 0; k < 8; ++k) {
        a[k] += __shfl_xor(a[k], 8, 64);
        a[k] += __shfl_xor(a[k], 16, 64);
        a[k] += __shfl_xor(a[k], 32, 64);
    }

    if (oct == 0) {   // lanes 0..7; lane l holds dims [8*l, 8*l+8)
        float dc = dis[c];
        size_t fo = (size_t)c * EMB + o8 * 8;
        if (!FUSE) {
            float s2 = dc * dc;               // z_new = dis^2 * sum
            uint4 v;
            v.x = ((uint)f2h(s2 * a[1]) << 16) | f2h(s2 * a[0]);
            v.y = ((uint)f2h(s2 * a[3]) << 16) | f2h(s2 * a[2]);
            v.z = ((uint)f2h(s2 * a[5]) << 16) | f2h(s2 * a[4]);
            v.w = ((uint)f2h(s2 * a[7]) << 16) | f2h(s2 * a[6]);
            *(uint4*)(zout + fo) = v;
        } else {
            // out = 0.25*(x + inv*(z1+z2) + dc*sum); inv = 1/dc (0 if deg=0)
            float inv = (dc > 0.0f) ? 1.0f / dc : 0.0f;
            uint4 v1 = *(const uint4*)(zprev + fo);
            uint4 v2 = *(const uint4*)(zin + fo);
            float4 x0, x1;
            if ((int)fo < n_user_elems) {
                x0 = *(const float4*)(user_w + fo);
                x1 = *(const float4*)(user_w + fo + 4);
            } else {
                size_t j = fo - n_user_elems;
                x0 = *(const float4*)(item_w + j);
                x1 = *(const float4*)(item_w + j + 4);
            }
            float2 p, q;
            float4 o0, o1;
            p = h2f2(v1.x); q = h2f2(v2.x);
            o0.x = 0.25f * (x0.x + inv * (p.x + q.x) + dc * a[0]);
            o0.y = 0.25f * (x0.y + inv * (p.y + q.y) + dc * a[1]);
            p = h2f2(v1.y); q = h2f2(v2.y);
            o0.z = 0.25f * (x0.z + inv * (p.x + q.x) + dc * a[2]);
            o0.w = 0.25f * (x0.w + inv * (p.y + q.y) + dc * a[3]);
            p = h2f2(v1.z); q = h2f2(v2.z);
            o1.x = 0.25f * (x1.x + inv * (p.x + q.x) + dc * a[4]);
            o1.y = 0.25f * (x1.y + inv * (p.y + q.y) + dc * a[5]);
            p = h2f2(v1.w); q = h2f2(v2.w);
            o1.z = 0.25f * (x1.z + inv * (p.x + q.x) + dc * a[6]);
            o1.w = 0.25f * (x1.w + inv * (p.y + q.y) + dc * a[7]);
            *(float4*)(out + fo) = o0;
            *(float4*)(out + fo + 4) = o1;
        }
    }
}

extern "C" void kernel_launch(void* const* d_in, const int* in_sizes, int n_in,
                              void* d_out, int out_size, void* d_ws, size_t ws_size,
                              hipStream_t stream) {
    // ---- role assignment by element count ----
    int ie = 0, iu = 1, ii = 2;
    {
        long long s[3] = { in_sizes[0], in_sizes[1], in_sizes[2] };
        ie = 0;
        if (s[1] > s[ie]) ie = 1;
        if (s[2] > s[ie]) ie = 2;
        int rest[2], k = 0;
        for (int j = 0; j < 3; ++j) if (j != ie) rest[k++] = j;
        if (s[rest[0]] >= s[rest[1]]) { iu = rest[0]; ii = rest[1]; }
        else                          { iu = rest[1]; ii = rest[0]; }
    }
    const int*   edge_index = (const int*)d_in[ie];
    const float* user_w     = (const float*)d_in[iu];
    const float* item_w     = (const float*)d_in[ii];
    float* out = (float*)d_out;

    const int n_edges = in_sizes[ie] / 2;
    const int n_users = in_sizes[iu] / EMB;
    const int n_items = in_sizes[ii] / EMB;
    const int n_nodes = n_users + n_items;
    const int n_elems = n_nodes * EMB;
    const int NB = (n_nodes + BNODES - 1) / BNODES;   // 1172
    const int nblk = (n_edges + CH - 1) / CH;         // 245

    // ---- workspace carve (byte-identical footprint to proven R19) ----
    // fp16 state buffers each have one extra zero row at node index n_nodes.
    // hist+runbase live in slot0's slack after pairs' 16MB (3.2MB slack >=
    // 2.3MB needed; lifetimes disjoint). Fallback appends only if short.
    auto align_up = [](size_t x) { return (x + 1023) & ~(size_t)1023; };
    char* w = (char*)d_ws;
    int*   flag       = (int*)w; w += 1024;
    int*   bcount     = (int*)w; w += align_up((size_t)NB * sizeof(int));
    int*   bucketBase = (int*)w; w += align_up(((size_t)NB + 1) * sizeof(int));
    int*   offsets    = (int*)w; w += align_up(((size_t)n_nodes + 1) * sizeof(int));
    float* dis        = (float*)w; w += align_up((size_t)n_nodes * sizeof(float));
    int*   csr_rows   = (int*)w; w += align_up((size_t)n_edges * sizeof(int));
    size_t u_bytes = align_up(((size_t)n_elems + EMB) * sizeof(ushort));
    size_t p_bytes = align_up((size_t)n_edges * sizeof(uint));
    size_t slot0   = (u_bytes > p_bytes ? u_bytes : p_bytes);
    size_t h_bytes = align_up((size_t)NB * nblk * sizeof(int));
    char*  slot0p = w;
    uint*  pairs  = (uint*)slot0p; w += slot0;
    ushort* z0    = (ushort*)w; w += u_bytes;
    ushort* z1    = (ushort*)w; w += u_bytes;
    ushort* z2    = (ushort*)w; w += u_bytes;
    int* hist; int* runbase;
    if (slot0 >= p_bytes + 2 * h_bytes) {
        hist    = (int*)(slot0p + p_bytes);
        runbase = (int*)(slot0p + p_bytes + h_bytes);
    } else {
        hist    = (int*)w; w += h_bytes;
        runbase = (int*)w; w += h_bytes;
    }

    // 0) setup: dtype detect + zero dummy rows
    lgcn_setup_kernel<<<1, 256, 0, stream>>>(edge_index, flag, z0, z1, z2,
                                             n_elems);

    // 1) atomic-free hist -> row scan -> bucket scan -> deterministic
    //    scatter -> bucket CSR(+init)
    lgcn_bhist2_kernel<<<nblk, STH, 0, stream>>>(
        edge_index, flag, hist, n_edges, n_nodes, NB, nblk);
    lgcn_rowscan_kernel<<<NB, 256, 0, stream>>>(hist, runbase, bcount, nblk);
    lgcn_bscan_kernel<<<1, 256, 0, stream>>>(bcount, bucketBase, offsets, NB, n_nodes);
    lgcn_bscatter4_kernel<<<nblk, STH, 0, stream>>>(
        edge_index, flag, bucketBase, hist, runbase, pairs,
        n_edges, n_nodes, NB, nblk);
    lgcn_bcsr_kernel<<<NB, 256, 0, stream>>>(
        pairs, bucketBase, user_w, item_w, offsets, csr_rows, dis, z0,
        n_users * EMB, n_nodes);

    // 2) 3 pull layers: z0 -> z1 -> z2 -> (fused) out
    {
        const int BLK = 256;   // 4 nodes/block
        long long n_thr = (long long)n_nodes * 64;
        int gW = (int)((n_thr + BLK - 1) / BLK);
        lgcn_gather_kernel<false><<<gW, BLK, 0, stream>>>(
            csr_rows, offsets, dis, z0, z1,
            nullptr, nullptr, nullptr, nullptr, 0, n_nodes);
        lgcn_gather_kernel<false><<<gW, BLK, 0, stream>>>(
            csr_rows, offsets, dis, z1, z2,
            nullptr, nullptr, nullptr, nullptr, 0, n_nodes);
        lgcn_gather_kernel<true><<<gW, BLK, 0, stream>>>(
            csr_rows, offsets, dis, z2, nullptr,
            z1, user_w, item_w, out, n_users * EMB, n_nodes);
    }
}

// Round 14
// 401.181 us; speedup vs baseline: 1.1322x; 1.0166x over previous
//
#include <hip/hip_runtime.h>
#include <hip/hip_fp16.h>

// LightGCN on MI355X — atomic-free bucket build + batched-MLP gather,
// deferred-total fp16 pipeline.
//
// R9:  bscatter 1024thr/CH=16384 (566->512).
// R10: batched 64-entry adjacency read + dis folded into state (512->481).
// R11: total deferred out of gathers; fp16 state; final pass (481->459).
// R12: bscatter pairs staged in LDS grouped by bucket (459->434).
// R13: FUSE final into g3 (WIN). R14/R15: gather plateau proven: 217MB/74us
//      and 259MB/86us are the SAME 3.0TB/s fetch rate (TCC fetch-bound).
//      R16: NT revert (454->422).
// R19: atomic-free bhist2+rowsum (422->417). R20: deterministic bscatter4
//      (no pass-1 edge read, no bcur atomics) (417->408). PROVEN BASE.
// R21: 3-change build consolidation died at container level (audited
//      clean; 3rd unexplained infra-correlated failure). Reverted.
// R22: exact R20 + ONE change: bcsr 256->512 threads (halves the serial
//      trip count of its two LDS-atomic passes + z0 init). Null result
//      => build at practical floor => declare roofline next round.

#ifndef EMB
#define EMB 64
#endif
#define BSHIFT 7                 // 128 nodes per bucket
#define BNODES (1 << BSHIFT)
#define NBMAX 1280               // LDS histogram capacity
#define CCAP 4800                // LDS pair-staging capacity per bucket
#define CH 16384                 // edges per chunk (bhist2/bscatter4)
#define STH 1024                 // threads per block (bhist2/bscatter4)
#define BCT 512                  // bcsr threads (R22)

typedef unsigned int uint;
typedef unsigned short ushort;

static __device__ __forceinline__ ushort f2h(float f) {
    __half h = __float2half(f);
    return *(ushort*)&h;
}

// u = two packed fp16; accumulate {lo,hi} into aL,aH (R12-proven form).
static __device__ __forceinline__ void acc2h(uint u, float& aL, float& aH) {
    __half2 h = *(__half2*)&u;
    float2 f = __half22float2(h);
    aL += f.x;
    aH += f.y;
}

static __device__ __forceinline__ float2 h2f2(uint u) {
    __half2 h = *(__half2*)&u;
    return __half22float2(h);
}

// ---- setup: dtype detect + zero dummy rows ----
__global__ void lgcn_setup_kernel(const int* __restrict__ ei,
                                  int* __restrict__ flag,
                                  ushort* __restrict__ z0,
                                  ushort* __restrict__ z1,
                                  ushort* __restrict__ z2,
                                  int n_elems) {
    __shared__ int any_nz;
    int t = threadIdx.x;
    if (t == 0) any_nz = 0;
    __syncthreads();
    if (t < 128 && ei[2 * t + 1] != 0) atomicOr(&any_nz, 1);
    if (t < EMB) {
        z0[n_elems + t] = 0;
        z1[n_elems + t] = 0;
        z2[n_elems + t] = 0;
    }
    __syncthreads();
    if (t == 0) *flag = (any_nz == 0) ? 1 : 0;
}

static __device__ __forceinline__ int load_idx(const int* __restrict__ ei,
                                               long long elem, int is64,
                                               int n_nodes) {
    int v = is64 ? ei[elem << 1] : ei[elem];
    return min(max(v, 0), n_nodes - 1);
}

// ---- build step 1: per-chunk bucket histogram, NO global atomics ----
__global__ void __launch_bounds__(STH)
lgcn_bhist2_kernel(const int* __restrict__ ei,
                   const int* __restrict__ flag,
                   int* __restrict__ hist,
                   int n_edges, int n_nodes, int NB, int nblk) {
    __shared__ int lcount[NBMAX];
    int t = threadIdx.x;
    int blk = blockIdx.x;
    int is64 = *flag;
    long long base = (long long)blk * CH;
    for (int i = t; i < NB; i += STH) lcount[i] = 0;
    __syncthreads();
    for (int k = t; k < CH; k += STH) {
        long long e = base + k;
        if (e < n_edges) {
            int c = load_idx(ei, (long long)n_edges + e, is64, n_nodes);
            atomicAdd(&lcount[c >> BSHIFT], 1);   // LDS only
        }
    }
    __syncthreads();
    for (int i = t; i < NB; i += STH)
        hist[(size_t)i * nblk + blk] = lcount[i];
}

// ---- build step 2a: per-bucket row scan: hist row -> runbase row, total ----
__global__ void lgcn_rowscan_kernel(const int* __restrict__ hist,
                                    int* __restrict__ runbase,
                                    int* __restrict__ bcount,
                                    int nblk) {
    __shared__ int tsum[256];
    int b = blockIdx.x;
    int t = threadIdx.x;            // 256 threads
    const int* row = hist + (size_t)b * nblk;
    int* orow = runbase + (size_t)b * nblk;
    int v = (t < nblk) ? row[t] : 0;    // nblk=245 <= 256
    tsum[t] = v;
    __syncthreads();
    for (int off = 1; off < 256; off <<= 1) {
        int x = (t >= off) ? tsum[t - off] : 0;
        __syncthreads();
        tsum[t] += x;
        __syncthreads();
    }
    if (t < nblk) orow[t] = tsum[t] - v;   // exclusive
    if (t == 255) bcount[b] = tsum[255];
}

// ---- build step 2b: exclusive scan of bucket counts (single block) ----
__global__ void lgcn_bscan_kernel(const int* __restrict__ bcount,
                                  int* __restrict__ bucketBase,
                                  int* __restrict__ offsets,
                                  int NB, int n_nodes) {
    __shared__ int tsum[256];
    int t = threadIdx.x;
    int K = (NB + 255) / 256;
    int base = t * K;
    int s = 0;
    for (int k = 0; k < K; ++k) {
        int i = base + k;
        if (i < NB) s += bcount[i];
    }
    tsum[t] = s;
    __syncthreads();
    for (int off = 1; off < 256; off <<= 1) {
        int x = (t >= off) ? tsum[t - off] : 0;
        __syncthreads();
        tsum[t] += x;
        __syncthreads();
    }
    int run = tsum[t] - s;
    for (int k = 0; k < K; ++k) {
        int i = base + k;
        if (i < NB) { bucketBase[i] = run; run += bcount[i]; }
    }
    if (t == 255) {
        bucketBase[NB] = tsum[255];
        offsets[n_nodes] = tsum[255];
    }
}

// ---- build step 3: deterministic LDS-staged pair scatter ----
// hist column replaces pass-1 edge read; ldelta from runbase (no atomics);
// stage + run-contiguous write as proven R12/bscatter3.
__global__ void __launch_bounds__(STH)
lgcn_bscatter4_kernel(const int* __restrict__ ei,
                      const int* __restrict__ flag,
                      const int* __restrict__ bucketBase,
                      const int* __restrict__ hist,
                      const int* __restrict__ runbase,
                      uint* __restrict__ pairs,
                      int n_edges, int n_nodes, int NB, int nblk) {
    __shared__ int lcount[NBMAX];   // counts, then staging cursor
    __shared__ int lloc[NBMAX];     // local staging base per bucket
    __shared__ int ldelta[NBMAX];   // global_run_base - local_base
    __shared__ int tsum[STH];
    __shared__ int ltot;
    __shared__ uint stage[CH];      // 64 KB pair staging
    __shared__ ushort stageb[CH];   // 32 KB bucket id per staged pair
    int t = threadIdx.x;
    int blk = blockIdx.x;
    int is64 = *flag;
    long long base = (long long)blk * CH;
    // load this chunk's histogram column
    for (int i = t; i < NB; i += STH)
        lcount[i] = hist[(size_t)i * nblk + blk];
    __syncthreads();
    // local exclusive scan lcount -> lloc (staging layout)
    {
        int K = (NB + STH - 1) / STH;
        int cbase = t * K;
        int s = 0;
        for (int k = 0; k < K; ++k) {
            int i = cbase + k;
            if (i < NB) s += lcount[i];
        }
        tsum[t] = s;
        __syncthreads();
        for (int off = 1; off < STH; off <<= 1) {
            int x = (t >= off) ? tsum[t - off] : 0;
            __syncthreads();
            tsum[t] += x;
            __syncthreads();
        }
        int run = tsum[t] - s;
        for (int k = 0; k < K; ++k) {
            int i = cbase + k;
            if (i < NB) { lloc[i] = run; run += lcount[i]; }
        }
        if (t == STH - 1) ltot = tsum[t];
    }
    __syncthreads();
    // deterministic reservation (no atomics)
    for (int i = t; i < NB; i += STH) {
        ldelta[i] = bucketBase[i] + runbase[(size_t)i * nblk + blk] - lloc[i];
        lcount[i] = 0;   // reuse as staging cursor
    }
    __syncthreads();
    // stage pairs grouped by bucket in LDS
    for (int k = t; k < CH; k += STH) {
        long long e = base + k;
        if (e < n_edges) {
            int r = load_idx(ei, e, is64, n_nodes);
            int c = load_idx(ei, (long long)n_edges + e, is64, n_nodes);
            int b = c >> BSHIFT;
            int pos = lloc[b] + atomicAdd(&lcount[b], 1);   // LDS only
            stage[pos] = ((uint)r << BSHIFT) | (uint)(c & (BNODES - 1));
            stageb[pos] = (ushort)b;
        }
    }
    __syncthreads();
    // coalesced run-contiguous global writes
    int tot = ltot;
    for (int k = t; k < tot; k += STH) {
        pairs[ldelta[stageb[k]] + k] = stage[k];
    }
}

// ---- build step 4: per-bucket CSR finalize + fused z0 init (512 thr) ----
__global__ void __launch_bounds__(BCT)
lgcn_bcsr_kernel(const uint* __restrict__ pairs,
                 const int* __restrict__ bucketBase,
                 const float* __restrict__ user_w,
                 const float* __restrict__ item_w,
                 int* __restrict__ offsets,
                 int* __restrict__ csr_rows,
                 float* __restrict__ dis,
                 ushort* __restrict__ z0,
                 int n_user_elems, int n_nodes) {
    __shared__ int deg[BNODES];
    __shared__ int tmp[BNODES];
    __shared__ int loffx[BNODES];
    __shared__ int cur[BNODES];
    __shared__ float disL[BNODES];
    __shared__ uint lp[CCAP];
    int b = blockIdx.x;
    int t = threadIdx.x;            // BCT=512 threads
    int nodeStart = b << BSHIFT;
    int base = bucketBase[b];
    int span = bucketBase[b + 1] - base;
    bool fits = (span <= CCAP);
    if (t < BNODES) deg[t] = 0;
    __syncthreads();
    for (int i = t; i < span; i += BCT) {
        uint p = pairs[base + i];
        if (fits) lp[i] = p;
        atomicAdd(&deg[p & (BNODES - 1)], 1);
    }
    __syncthreads();
    if (t < BNODES) tmp[t] = deg[t];
    __syncthreads();
    for (int off = 1; off < BNODES; off <<= 1) {
        int x = (t < BNODES && t >= off) ? tmp[t - off] : 0;
        __syncthreads();
        if (t < BNODES) tmp[t] += x;
        __syncthreads();
    }
    if (t < BNODES) {
        int excl = tmp[t] - deg[t];
        loffx[t] = excl;
        cur[t] = 0;
        float d = (deg[t] > 0) ? rsqrtf((float)deg[t]) : 0.0f;
        disL[t] = d;
        int node = nodeStart + t;
        if (node < n_nodes) {
            offsets[node] = base + excl;
            dis[node] = d;
        }
    }
    __syncthreads();
    for (int i = t; i < span; i += BCT) {
        uint p = fits ? lp[i] : pairs[base + i];
        int cl = (int)(p & (BNODES - 1));
        int pos = loffx[cl] + atomicAdd(&cur[cl], 1);
        csr_rows[base + pos] = (int)(p >> BSHIFT);
    }
    // fused init: z0 rows for this bucket's nodes, z0 = fp16(dis * x)
    int eBase = nodeStart << 6;               // first element of this bucket
    for (int e4 = t; e4 < (BNODES << 4); e4 += BCT) {   // float4 granules
        int e = e4 << 2;
        int node = nodeStart + (e >> 6);
        if (node < n_nodes) {
            int gi = eBase + e;
            float4 v = (gi < n_user_elems)
                ? *(const float4*)(user_w + gi)
                : *(const float4*)(item_w + (gi - n_user_elems));
            float d = disL[e >> 6];
            ushort4 o;
            o.x = f2h(d * v.x); o.y = f2h(d * v.y);
            o.z = f2h(d * v.z); o.w = f2h(d * v.w);
            *(ushort4*)(z0 + gi) = o;
        }
    }
}

// gather: one wave per node; 8 lanes per edge (uint4 = 16B per lane).
// R12-proven body: scalar acc2h into a[8]; up to 64 adjacency entries in
// one coalesced csr read; all row gathers back-to-back.
// FUSE (layer 3): epilogue computes out = 0.25*(x + inv*(z1+z2) + dc*sum).
template <bool FUSE>
__global__ void lgcn_gather_kernel(const int* __restrict__ csr_rows,
                                   const int* __restrict__ offsets,
                                   const float* __restrict__ dis,
                                   const ushort* __restrict__ zin,
                                   ushort* __restrict__ zout,
                                   const ushort* __restrict__ zprev,
                                   const float* __restrict__ user_w,
                                   const float* __restrict__ item_w,
                                   float* __restrict__ out,
                                   int n_user_elems, int n_nodes) {
    long long tid = (long long)blockIdx.x * blockDim.x + threadIdx.x;
    int c    = (int)(tid >> 6);
    int lane = threadIdx.x & 63;
    int oct  = lane >> 3;   // edge slot 0..7 within a group
    int o8   = lane & 7;    // which 16B chunk of the 128B row
    if (c >= n_nodes) return;
    int beg = offsets[c];
    int end = offsets[c + 1];
    int deg = end - beg;
    float a[8];
    #pragma unroll
    for (int k = 0; k < 8; ++k) a[k] = 0.0f;

    if (deg > 0) {
        int n1 = deg < 64 ? deg : 64;
        int ng = (n1 + 7) >> 3;        // active groups (wave-uniform)
        int rr[8];
        #pragma unroll
        for (int g = 0; g < 8; ++g) {
            int s = g * 8 + oct;
            if (g < ng) {
                int r = csr_rows[beg + (s < n1 ? s : 0)];
                rr[g] = (s < n1) ? r : n_nodes;      // zero row for tail
            } else {
                rr[g] = n_nodes;
            }
        }
        uint4 q[8];
        #pragma unroll
        for (int g = 0; g < 8; ++g)
            if (g < ng)
                q[g] = *(const uint4*)(zin + (size_t)rr[g] * EMB + o8 * 8);
        #pragma unroll
        for (int g = 0; g < 8; ++g) {
            if (g < ng) {
                acc2h(q[g].x, a[0], a[1]);
                acc2h(q[g].y, a[2], a[3]);
                acc2h(q[g].z, a[4], a[5]);
                acc2h(q[g].w, a[6], a[7]);
            }
        }
        // rare tail: deg > 64
        for (int j = beg + 64; j < end; j += 16) {
            int j0 = j + oct;
            int j1 = j + 8 + oct;
            bool v0 = j0 < end;
            bool v1 = j1 < end;
            int r0 = csr_rows[v0 ? j0 : beg]; r0 = v0 ? r0 : n_nodes;
            int r1 = csr_rows[v1 ? j1 : beg]; r1 = v1 ? r1 : n_nodes;
            uint4 q0 = *(const uint4*)(zin + (size_t)r0 * EMB + o8 * 8);
            uint4 q1 = *(const uint4*)(zin + (size_t)r1 * EMB + o8 * 8);
            acc2h(q0.x, a[0], a[1]);
            acc2h(q0.y, a[2], a[3]);
            acc2h(q0.z, a[4], a[5]);
            acc2h(q0.w, a[6], a[7]);
            acc2h(q1.x, a[0], a[1]);
            acc2h(q1.y, a[2], a[3]);
            acc2h(q1.z, a[4], a[5]);
            acc2h(q1.w, a[6], a[7]);
        }
    }

    #pragma unroll
    for (int k = 0; k < 8; ++k) {
        a[k] += __shfl_xor(a[k], 8, 64);
        a[k] += __shfl_xor(a[k], 16, 64);
        a[k] += __shfl_xor(a[k], 32, 64);
    }

    if (oct == 0) {   // lanes 0..7; lane l holds dims [8*l, 8*l+8)
        float dc = dis[c];
        size_t fo = (size_t)c * EMB + o8 * 8;
        if (!FUSE) {
            float s2 = dc * dc;               // z_new = dis^2 * sum
            uint4 v;
            v.x = ((uint)f2h(s2 * a[1]) << 16) | f2h(s2 * a[0]);
            v.y = ((uint)f2h(s2 * a[3]) << 16) | f2h(s2 * a[2]);
            v.z = ((uint)f2h(s2 * a[5]) << 16) | f2h(s2 * a[4]);
            v.w = ((uint)f2h(s2 * a[7]) << 16) | f2h(s2 * a[6]);
            *(uint4*)(zout + fo) = v;
        } else {
            // out = 0.25*(x + inv*(z1+z2) + dc*sum); inv = 1/dc (0 if deg=0)
            float inv = (dc > 0.0f) ? 1.0f / dc : 0.0f;
            uint4 v1 = *(const uint4*)(zprev + fo);
            uint4 v2 = *(const uint4*)(zin + fo);
            float4 x0, x1;
            if ((int)fo < n_user_elems) {
                x0 = *(const float4*)(user_w + fo);
                x1 = *(const float4*)(user_w + fo + 4);
            } else {
                size_t j = fo - n_user_elems;
                x0 = *(const float4*)(item_w + j);
                x1 = *(const float4*)(item_w + j + 4);
            }
            float2 p, q;
            float4 o0, o1;
            p = h2f2(v1.x); q = h2f2(v2.x);
            o0.x = 0.25f * (x0.x + inv * (p.x + q.x) + dc * a[0]);
            o0.y = 0.25f * (x0.y + inv * (p.y + q.y) + dc * a[1]);
            p = h2f2(v1.y); q = h2f2(v2.y);
            o0.z = 0.25f * (x0.z + inv * (p.x + q.x) + dc * a[2]);
            o0.w = 0.25f * (x0.w + inv * (p.y + q.y) + dc * a[3]);
            p = h2f2(v1.z); q = h2f2(v2.z);
            o1.x = 0.25f * (x1.x + inv * (p.x + q.x) + dc * a[4]);
            o1.y = 0.25f * (x1.y + inv * (p.y + q.y) + dc * a[5]);
            p = h2f2(v1.w); q = h2f2(v2.w);
            o1.z = 0.25f * (x1.z + inv * (p.x + q.x) + dc * a[6]);
            o1.w = 0.25f * (x1.w + inv * (p.y + q.y) + dc * a[7]);
            *(float4*)(out + fo) = o0;
            *(float4*)(out + fo + 4) = o1;
        }
    }
}

extern "C" void kernel_launch(void* const* d_in, const int* in_sizes, int n_in,
                              void* d_out, int out_size, void* d_ws, size_t ws_size,
                              hipStream_t stream) {
    // ---- role assignment by element count ----
    int ie = 0, iu = 1, ii = 2;
    {
        long long s[3] = { in_sizes[0], in_sizes[1], in_sizes[2] };
        ie = 0;
        if (s[1] > s[ie]) ie = 1;
        if (s[2] > s[ie]) ie = 2;
        int rest[2], k = 0;
        for (int j = 0; j < 3; ++j) if (j != ie) rest[k++] = j;
        if (s[rest[0]] >= s[rest[1]]) { iu = rest[0]; ii = rest[1]; }
        else                          { iu = rest[1]; ii = rest[0]; }
    }
    const int*   edge_index = (const int*)d_in[ie];
    const float* user_w     = (const float*)d_in[iu];
    const float* item_w     = (const float*)d_in[ii];
    float* out = (float*)d_out;

    const int n_edges = in_sizes[ie] / 2;
    const int n_users = in_sizes[iu] / EMB;
    const int n_items = in_sizes[ii] / EMB;
    const int n_nodes = n_users + n_items;
    const int n_elems = n_nodes * EMB;
    const int NB = (n_nodes + BNODES - 1) / BNODES;   // 1172
    const int nblk = (n_edges + CH - 1) / CH;         // 245

    // ---- workspace carve (byte-identical footprint to proven R20) ----
    // fp16 state buffers each have one extra zero row at node index n_nodes.
    // hist+runbase live in slot0's slack after pairs' 16MB (3.2MB slack >=
    // 2.3MB needed; lifetimes disjoint). Fallback appends only if short.
    auto align_up = [](size_t x) { return (x + 1023) & ~(size_t)1023; };
    char* w = (char*)d_ws;
    int*   flag       = (int*)w; w += 1024;
    int*   bcount     = (int*)w; w += align_up((size_t)NB * sizeof(int));
    int*   bucketBase = (int*)w; w += align_up(((size_t)NB + 1) * sizeof(int));
    int*   offsets    = (int*)w; w += align_up(((size_t)n_nodes + 1) * sizeof(int));
    float* dis        = (float*)w; w += align_up((size_t)n_nodes * sizeof(float));
    int*   csr_rows   = (int*)w; w += align_up((size_t)n_edges * sizeof(int));
    size_t u_bytes = align_up(((size_t)n_elems + EMB) * sizeof(ushort));
    size_t p_bytes = align_up((size_t)n_edges * sizeof(uint));
    size_t slot0   = (u_bytes > p_bytes ? u_bytes : p_bytes);
    size_t h_bytes = align_up((size_t)NB * nblk * sizeof(int));
    char*  slot0p = w;
    uint*  pairs  = (uint*)slot0p; w += slot0;
    ushort* z0    = (ushort*)w; w += u_bytes;
    ushort* z1    = (ushort*)w; w += u_bytes;
    ushort* z2    = (ushort*)w; w += u_bytes;
    int* hist; int* runbase;
    if (slot0 >= p_bytes + 2 * h_bytes) {
        hist    = (int*)(slot0p + p_bytes);
        runbase = (int*)(slot0p + p_bytes + h_bytes);
    } else {
        hist    = (int*)w; w += h_bytes;
        runbase = (int*)w; w += h_bytes;
    }

    // 0) setup: dtype detect + zero dummy rows
    lgcn_setup_kernel<<<1, 256, 0, stream>>>(edge_index, flag, z0, z1, z2,
                                             n_elems);

    // 1) atomic-free hist -> row scan -> bucket scan -> deterministic
    //    scatter -> bucket CSR(+init)
    lgcn_bhist2_kernel<<<nblk, STH, 0, stream>>>(
        edge_index, flag, hist, n_edges, n_nodes, NB, nblk);
    lgcn_rowscan_kernel<<<NB, 256, 0, stream>>>(hist, runbase, bcount, nblk);
    lgcn_bscan_kernel<<<1, 256, 0, stream>>>(bcount, bucketBase, offsets, NB, n_nodes);
    lgcn_bscatter4_kernel<<<nblk, STH, 0, stream>>>(
        edge_index, flag, bucketBase, hist, runbase, pairs,
        n_edges, n_nodes, NB, nblk);
    lgcn_bcsr_kernel<<<NB, BCT, 0, stream>>>(
        pairs, bucketBase, user_w, item_w, offsets, csr_rows, dis, z0,
        n_users * EMB, n_nodes);

    // 2) 3 pull layers: z0 -> z1 -> z2 -> (fused) out
    {
        const int BLK = 256;   // 4 nodes/block
        long long n_thr = (long long)n_nodes * 64;
        int gW = (int)((n_thr + BLK - 1) / BLK);
        lgcn_gather_kernel<false><<<gW, BLK, 0, stream>>>(
            csr_rows, offsets, dis, z0, z1,
            nullptr, nullptr, nullptr, nullptr, 0, n_nodes);
        lgcn_gather_kernel<false><<<gW, BLK, 0, stream>>>(
            csr_rows, offsets, dis, z1, z2,
            nullptr, nullptr, nullptr, nullptr, 0, n_nodes);
        lgcn_gather_kernel<true><<<gW, BLK, 0, stream>>>(
            csr_rows, offsets, dis, z2, nullptr,
            z1, user_w, item_w, out, n_users * EMB, n_nodes);
    }
}